// Round 8
// baseline (9525.327 us; speedup 1.0000x reference)
//
#include <hip/hip_runtime.h>
#include <cstdint>
#include <cstddef>

constexpr int N_NODES = 65536;
constexpr int D       = 128;
constexpr int E_EDGES = 524288;
constexpr int LVLS    = 8;
constexpr int EL      = E_EDGES / LVLS;   // 65536

typedef unsigned int  u32;
typedef unsigned short u16;
typedef __attribute__((ext_vector_type(8)))  short short8;   // 8 bf16 (4 VGPR)
typedef __attribute__((ext_vector_type(16))) float f32x16;

__device__ __forceinline__ float sigmoidf_(float x) { return 1.0f / (1.0f + expf(-x)); }

__device__ __forceinline__ u32 bf_hi(float f) {           // f32 -> bf16 bits (RNE)
    u32 x = __float_as_uint(f);
    return (x + 0x7fffu + ((x >> 16) & 1u)) >> 16;
}
__device__ __forceinline__ float bf_f(u32 hbits) { return __uint_as_float(hbits << 16); }

// Swizzled byte offset inside a [rows][32 bf16] LDS tile (64B rows).
// XOR of bits 4-5 only: bijective within each 64B row (4x16B slot permute).
__device__ __forceinline__ int swz(int row, int kbyte) {
    return row * 64 + (kbyte ^ ((row & 3) << 4));
}

__device__ __forceinline__ float wave_sum(float v) {
#pragma unroll
    for (int off = 32; off > 0; off >>= 1) v += __shfl_down(v, off, 64);
    return v;
}

// ---------------------------------------------------------------------------
// u_dir[c] = sum_d We[d][c]*wa2[d];  cst = be.wa2 + ba
__global__ __launch_bounds__(256)
void prep_kernel(const float* __restrict__ We_f, const float* __restrict__ Wa_f,
                 const float* __restrict__ be_f, const float* __restrict__ ba_f,
                 const float* __restrict__ We_b, const float* __restrict__ Wa_b,
                 const float* __restrict__ be_b, const float* __restrict__ ba_b,
                 float* __restrict__ u_f, float* __restrict__ u_b, float* __restrict__ cst)
{
    int t = threadIdx.x;
    if (t < 128) {
        float s = 0.f;
        for (int d = 0; d < 128; ++d) s = fmaf(We_f[d * 128 + t], Wa_f[128 + d], s);
        u_f[t] = s;
    } else {
        int c = t - 128;
        float s = 0.f;
        for (int d = 0; d < 128; ++d) s = fmaf(We_b[d * 128 + c], Wa_b[128 + d], s);
        u_b[c] = s;
    }
    if (t == 0) {
        float s = 0.f;
        for (int d = 0; d < 128; ++d) s = fmaf(be_f[d], Wa_f[128 + d], s);
        cst[0] = s + ba_f[0];
    }
    if (t == 255) {
        float s = 0.f;
        for (int d = 0; d < 128; ++d) s = fmaf(be_b[d], Wa_b[128 + d], s);
        cst[1] = s + ba_b[0];
    }
}

// ---------------------------------------------------------------------------
// all 4 weight matrices -> bf16 hi/lo; wsel = blockIdx.y in {WiF,WhF,WiB,WhB}
__global__ __launch_bounds__(256)
void convert_w4(const float* __restrict__ W0, const float* __restrict__ W1,
                const float* __restrict__ W2, const float* __restrict__ W3,
                u16* __restrict__ hi, u16* __restrict__ lo)
{
    const float* Ws[4] = {W0, W1, W2, W3};
    int wsel = blockIdx.y;
    int i = blockIdx.x * 256 + threadIdx.x;        // < 49152
    float v = Ws[wsel][i];
    u32 hb = bf_hi(v);
    hi[wsel * 49152 + i] = (u16)hb;
    lo[wsel * 49152 + i] = (u16)bf_hi(v - bf_f(hb));
}

// ---------------------------------------------------------------------------
__global__ __launch_bounds__(256)
void edot_kernel(const float* __restrict__ ea, const float* __restrict__ u_f,
                 const float* __restrict__ u_b, const float* __restrict__ cst,
                 float* __restrict__ edot_f, float* __restrict__ edot_b)
{
    int wv = threadIdx.x >> 6, lane = threadIdx.x & 63;
    int e = blockIdx.x * 4 + wv;
    if (e >= E_EDGES) return;
    int d = lane << 1;
    float2 v  = *reinterpret_cast<const float2*>(ea + (size_t)e * 128 + d);
    float2 uf = *reinterpret_cast<const float2*>(u_f + d);
    float2 ub = *reinterpret_cast<const float2*>(u_b + d);
    float af = wave_sum(v.x * uf.x + v.y * uf.y);
    float ab = wave_sum(v.x * ub.x + v.y * ub.y);
    if (lane == 0) {
        edot_f[e] = af + cst[0];
        edot_b[e] = ab + cst[1];
    }
}

// ---------------------------------------------------------------------------
// per-(dir,level) target counts + direction flags. dl = dir*8+lvl.
__global__ __launch_bounds__(256)
void count_flags(const int* __restrict__ ei, int* __restrict__ counts,
                 int* __restrict__ flag_f, int* __restrict__ flag_b)
{
    int e = blockIdx.x * 256 + threadIdx.x;
    int lv = e >> 16;
    int s = ei[e], t = ei[E_EDGES + e];
    atomicAdd(&counts[(size_t)lv * 65536 + t], 1);           // fwd: target = dst
    atomicAdd(&counts[(size_t)(8 + lv) * 65536 + s], 1);     // bwd: target = src
    flag_f[t] = 1;
    flag_b[s] = 1;
}

// ---------------------------------------------------------------------------
// exclusive scan of each 65536-count segment -> offs[65537] per segment
__global__ __launch_bounds__(1024)
void scan_kernel(const int* __restrict__ counts, int* __restrict__ offs)
{
    __shared__ int sbuf[1024];
    int dl = blockIdx.x;
    const int* c = counts + (size_t)dl * 65536;
    int* o = offs + (size_t)dl * 65537;
    int t = threadIdx.x;
    int base = t * 64;
    int s = 0;
    for (int k = 0; k < 64; ++k) s += c[base + k];
    sbuf[t] = s;
    __syncthreads();
    int val = s;
    for (int off = 1; off < 1024; off <<= 1) {
        int add = (t >= off) ? sbuf[t - off] : 0;
        __syncthreads();
        val += add;
        sbuf[t] = val;
        __syncthreads();
    }
    int run = val - s;                 // exclusive prefix
    for (int k = 0; k < 64; ++k) { o[base + k] = run; run += c[base + k]; }
    if (t == 1023) o[65536] = val;
}

// ---------------------------------------------------------------------------
// fill CSR entries: per edge, slot = dl*EL + offs[i] + cursor++ ; store (j, edot)
__global__ __launch_bounds__(256)
void fill_csr(const int* __restrict__ ei, const float* __restrict__ edot_f,
              const float* __restrict__ edot_b, const int* __restrict__ offs,
              int* __restrict__ cursor, int* __restrict__ csr_j,
              float* __restrict__ csr_edot)
{
    int idx = blockIdx.x * 256 + threadIdx.x;       // < 2E
    int dir = idx >= E_EDGES;
    int ge = dir ? idx - E_EDGES : idx;
    int lv = ge >> 16;
    int dl = dir * 8 + lv;
    int i = dir ? ei[ge] : ei[E_EDGES + ge];
    int j = dir ? ei[E_EDGES + ge] : ei[ge];
    int pos = offs[(size_t)dl * 65537 + i] + atomicAdd(&cursor[(size_t)dl * 65536 + i], 1);
    int slot = dl * EL + pos;
    csr_j[slot] = j;
    csr_edot[slot] = dir ? edot_b[ge] : edot_f[ge];
}

// ---------------------------------------------------------------------------
// compact per-(dir,lvl) target list
__global__ __launch_bounds__(256)
void compact_kernel(const int* __restrict__ counts, int* __restrict__ rows,
                    int* __restrict__ cnts)
{
    int idx = blockIdx.x * 256 + threadIdx.x;       // < 16*65536
    int dl = idx >> 16, n = idx & 65535;
    if (counts[idx] > 0) {
        int r = atomicAdd(&cnts[dl], 1);
        rows[(size_t)dl * 65536 + r] = n;
    }
}

// ---------------------------------------------------------------------------
// wave per target: single-pass softmax-weighted aggregation, compacted output.
// msgc[r] = (sum_e exp(alpha_e) * h[j_e]) / (sum_e exp(alpha_e))
__global__ __launch_bounds__(256)
void attn_msg(const int* __restrict__ pcnt, const int* __restrict__ rows,
              const int* __restrict__ offs, const int* __restrict__ csr_j,
              const float* __restrict__ csr_edot, const float* __restrict__ qdot,
              const float* __restrict__ hdot, const float* __restrict__ h,
              float* __restrict__ msgc)
{
    int cnt = *pcnt;
    int lane = threadIdx.x & 63;
    int wid = (blockIdx.x * 256 + threadIdx.x) >> 6;
    int nw = (gridDim.x * 256) >> 6;
    int d = lane << 1;
    for (int r = wid; r < cnt; r += nw) {
        int i = rows[r];
        int o0 = offs[i], o1 = offs[i + 1];
        float qi = qdot[i];
        float den = 0.f, ax = 0.f, ay = 0.f;
        for (int e = o0; e < o1; ++e) {
            int j = csr_j[e];
            float ex = expf(qi + hdot[j] + csr_edot[e]);
            float2 hv = *reinterpret_cast<const float2*>(h + (size_t)j * 128 + d);
            den += ex;
            ax = fmaf(ex, hv.x, ax);
            ay = fmaf(ex, hv.y, ay);
        }
        float inv = 1.f / den;
        *reinterpret_cast<float2*>(msgc + (size_t)r * 128 + d) = make_float2(ax * inv, ay * inv);
    }
}

// ---------------------------------------------------------------------------
// Fused split-bf16 MFMA GEMM (C = A @ W^T, K=128, Ncols=384) + GRU epilogue.
// MODE 0: A=h_prev [65536,128], W=Wi. gi(+bi) for flagged, h-init for roots,
//         qdot, hdot.
// MODE 1: A=msgc [cnt,128] DENSE, W=Wh. Full GRU (hidden=msgc row), scatter
//         h/hdot via rows[].
template<int MODE>
__global__ __launch_bounds__(512, 2)
void gemm_fused(const float* __restrict__ A,
                const u16* __restrict__ Whi, const u16* __restrict__ Wlo,
                const int* __restrict__ pcnt, const int* __restrict__ rows,
                const float* __restrict__ bi,
                const float* __restrict__ bh,
                const float* __restrict__ wa,
                const int* __restrict__ flag,
                float* __restrict__ gi,
                float* __restrict__ h,
                float* __restrict__ hdot, float* __restrict__ qdot)
{
    __shared__ __align__(16) unsigned char smem[16384 + 49152 + 4096 + 512];
    unsigned char* As = smem;               // [2 halves][128][32 bf16] swizzled
    unsigned char* Bs = smem + 16384;       // [2 halves][384][32 bf16] swizzled
    float* red   = (float*)(smem + 16384 + 49152);      // [128][4] (+[128][4] qdot)
    int* rowsLds = (int*)(smem + 16384 + 49152 + 4096); // [128]

    const int tid = threadIdx.x;
    int cnt;
    if constexpr (MODE == 0) cnt = N_NODES; else cnt = *pcnt;
    const int row0 = blockIdx.x * 128;
    if (row0 >= cnt) return;

    if constexpr (MODE == 1) {
        if (tid < 128) rowsLds[tid] = rows[row0 + tid];   // beyond-cnt: garbage, masked later
        __syncthreads();
    }

    f32x16 acc[2][3];
#pragma unroll
    for (int mt = 0; mt < 2; ++mt)
#pragma unroll
        for (int g = 0; g < 3; ++g) acc[mt][g] = (f32x16)0.0f;

    const int lane = tid & 63, wv = tid >> 6;
    const int q = wv & 3, mh = wv >> 2;
    const int l31 = lane & 31, l5 = lane >> 5;

    for (int k0 = 0; k0 < 128; k0 += 32) {
        // ---- stage A (f32 -> bf16 hi/lo): 128 rows x 32 k (dense in both modes)
#pragma unroll
        for (int p = 0; p < 2; ++p) {
            int idx = tid + p * 512;
            int rw = idx >> 3, kf = (idx & 7) << 2;
            float4 v = *reinterpret_cast<const float4*>(A + (size_t)(row0 + rw) * 128 + k0 + kf);
            u32 h0 = bf_hi(v.x), h1 = bf_hi(v.y), h2 = bf_hi(v.z), h3 = bf_hi(v.w);
            u32 l0 = bf_hi(v.x - bf_f(h0)), l1 = bf_hi(v.y - bf_f(h1));
            u32 l2 = bf_hi(v.z - bf_f(h2)), l3 = bf_hi(v.w - bf_f(h3));
            int off = swz(rw, kf * 2);
            *reinterpret_cast<uint2*>(As + off)        = make_uint2(h0 | (h1 << 16), h2 | (h3 << 16));
            *reinterpret_cast<uint2*>(As + 8192 + off) = make_uint2(l0 | (l1 << 16), l2 | (l3 << 16));
        }
        // ---- stage B (preconverted bf16 hi/lo): 384 rows x 32 k x 2 halves
#pragma unroll
        for (int p = 0; p < 6; ++p) {
            int c = tid + p * 512;
            int hf = c & 1, cc = c >> 1;
            int rw = cc >> 2, kc = cc & 3;
            const u16* src = hf ? Wlo : Whi;
            uint4 v = *reinterpret_cast<const uint4*>(src + (size_t)rw * 128 + k0 + kc * 8);
            *reinterpret_cast<uint4*>(Bs + hf * 24576 + swz(rw, kc * 16)) = v;
        }
        __syncthreads();
        // ---- MFMA
#pragma unroll
        for (int kh = 0; kh < 2; ++kh) {
            short8 a[2][2], b[3][2];
#pragma unroll
            for (int mt = 0; mt < 2; ++mt)
#pragma unroll
                for (int hf = 0; hf < 2; ++hf)
                    a[mt][hf] = *reinterpret_cast<const short8*>(
                        As + hf * 8192 + swz(mh * 64 + mt * 32 + l31, kh * 32 + l5 * 16));
#pragma unroll
            for (int g = 0; g < 3; ++g)
#pragma unroll
                for (int hf = 0; hf < 2; ++hf)
                    b[g][hf] = *reinterpret_cast<const short8*>(
                        Bs + hf * 24576 + swz(q * 32 + g * 128 + l31, kh * 32 + l5 * 16));
#pragma unroll
            for (int mt = 0; mt < 2; ++mt)
#pragma unroll
                for (int g = 0; g < 3; ++g) {
                    acc[mt][g] = __builtin_amdgcn_mfma_f32_32x32x16_bf16(a[mt][0], b[g][0], acc[mt][g], 0, 0, 0);
                    acc[mt][g] = __builtin_amdgcn_mfma_f32_32x32x16_bf16(a[mt][0], b[g][1], acc[mt][g], 0, 0, 0);
                    acc[mt][g] = __builtin_amdgcn_mfma_f32_32x32x16_bf16(a[mt][1], b[g][0], acc[mt][g], 0, 0, 0);
                }
        }
        __syncthreads();
    }

    // ---- epilogue
    const int d = q * 32 + l31;
    const float wa2d = wa[128 + d];
    const float bh0 = bh[d], bh1 = bh[d + 128], bh2 = bh[d + 256];
    float bi0 = 0.f, bi1 = 0.f, bi2 = 0.f, wa1d = 0.f;
    if constexpr (MODE == 0) {
        bi0 = bi[d]; bi1 = bi[d + 128]; bi2 = bi[d + 256]; wa1d = wa[d];
    }

#pragma unroll
    for (int mt = 0; mt < 2; ++mt)
#pragma unroll
        for (int rg = 0; rg < 16; ++rg) {
            int rl = mh * 64 + mt * 32 + (rg & 3) + ((rg >> 2) << 3) + (l5 << 2);
            int gr = row0 + rl;
            float hv = 0.f, pq = 0.f;
            if constexpr (MODE == 0) {
                int n = gr;
                int fl = flag[n];
                float g0 = acc[mt][0][rg] + bi0;
                float g1 = acc[mt][1][rg] + bi1;
                float g2 = acc[mt][2][rg] + bi2;
                if (fl) {
                    gi[(size_t)n * 384 + d]       = g0;
                    gi[(size_t)n * 384 + d + 128] = g1;
                    gi[(size_t)n * 384 + d + 256] = g2;
                } else {
                    float rr = sigmoidf_(g0 + bh0);
                    float zz = sigmoidf_(g1 + bh1);
                    float nn = tanhf(g2 + rr * bh2);
                    hv = (1.f - zz) * nn;          // hidden = 0 for roots
                }
                h[(size_t)n * 128 + d] = hv;
                pq = A[(size_t)n * 128 + d] * wa1d;  // A == h_prev
            } else {
                bool ok = gr < cnt;
                int n = ok ? rowsLds[rl] : 0;
                const float* gin = gi + (size_t)n * 384;
                float mval = A[(size_t)gr * 128 + d];   // hidden = msg (dense row)
                float rr = sigmoidf_(gin[d]       + acc[mt][0][rg] + bh0);
                float zz = sigmoidf_(gin[d + 128] + acc[mt][1][rg] + bh1);
                float nn = tanhf(gin[d + 256] + rr * (acc[mt][2][rg] + bh2));
                hv = (1.f - zz) * nn + zz * mval;
                if (ok) h[(size_t)n * 128 + d] = hv;
            }
            float pd = hv * wa2d;
#pragma unroll
            for (int o = 1; o < 32; o <<= 1) pd += __shfl_xor(pd, o, 64);
            if constexpr (MODE == 0) {
#pragma unroll
                for (int o = 1; o < 32; o <<= 1) pq += __shfl_xor(pq, o, 64);
            }
            if (l31 == 0) {
                red[rl * 4 + q] = pd;
                if constexpr (MODE == 0) red[512 + rl * 4 + q] = pq;
            }
        }
    __syncthreads();
    if (tid < 128) {
        int gr = row0 + tid;
        if (gr < cnt) {
            int n;
            if constexpr (MODE == 0) n = gr; else n = rowsLds[tid];
            hdot[n] = red[tid * 4] + red[tid * 4 + 1] + red[tid * 4 + 2] + red[tid * 4 + 3];
            if constexpr (MODE == 0)
                qdot[n] = red[512 + tid * 4] + red[512 + tid * 4 + 1] +
                          red[512 + tid * 4 + 2] + red[512 + tid * 4 + 3];
        }
    }
}

// ---------------------------------------------------------------------------
__global__ __launch_bounds__(256)
void relu_kernel(const float* __restrict__ h, float* __restrict__ out)
{
    int idx = (blockIdx.x * 256 + threadIdx.x) * 4;
    float4 v = *reinterpret_cast<const float4*>(h + idx);
    v.x = fmaxf(v.x, 0.f); v.y = fmaxf(v.y, 0.f);
    v.z = fmaxf(v.z, 0.f); v.w = fmaxf(v.w, 0.f);
    *reinterpret_cast<float4*>(out + idx) = v;
}

// ---------------------------------------------------------------------------
extern "C" void kernel_launch(void* const* d_in, const int* in_sizes, int n_in,
                              void* d_out, int out_size, void* d_ws, size_t ws_size,
                              hipStream_t stream)
{
    (void)in_sizes; (void)n_in; (void)out_size; (void)ws_size;

    const float* x    = (const float*)d_in[0];
    const int*   ei   = (const int*)d_in[1];
    const float* ea   = (const float*)d_in[2];
    const float* We_f = (const float*)d_in[4];
    const float* be_f = (const float*)d_in[5];
    const float* Wa_f = (const float*)d_in[6];
    const float* ba_f = (const float*)d_in[7];
    const float* Wi_f = (const float*)d_in[8];
    const float* Wh_f = (const float*)d_in[9];
    const float* bi_f = (const float*)d_in[10];
    const float* bh_f = (const float*)d_in[11];
    const float* We_b = (const float*)d_in[12];
    const float* be_b = (const float*)d_in[13];
    const float* Wa_b = (const float*)d_in[14];
    const float* ba_b = (const float*)d_in[15];
    const float* Wi_b = (const float*)d_in[16];
    const float* Wh_b = (const float*)d_in[17];
    const float* bi_b = (const float*)d_in[18];
    const float* bh_b = (const float*)d_in[19];
    float* out = (float*)d_out;

    char* p = (char*)d_ws;
    auto carve = [&](size_t bytes) -> char* {
        char* r = p;
        p += (bytes + 255) & ~(size_t)255;
        return r;
    };
    // ---- zeroed region (contiguous, one memset per launch) ----
    int*   counts  = (int*)carve((size_t)16 * 65536 * 4);      // [dir*8+lvl][node]
    int*   cursor  = (int*)carve((size_t)16 * 65536 * 4);
    int*   cnts    = (int*)carve(256);                         // 16 used
    int*   flag_f  = (int*)carve((size_t)N_NODES * 4);
    int*   flag_b  = (int*)carve((size_t)N_NODES * 4);
    size_t zbytes  = (size_t)((char*)flag_b - (char*)counts) + (size_t)N_NODES * 4;
    // ---- rest (fully overwritten each launch before use) ----
    u16*   W_hi    = (u16*)carve((size_t)4 * 49152 * 2);       // WiF,WhF,WiB,WhB
    u16*   W_lo    = (u16*)carve((size_t)4 * 49152 * 2);
    float* u_f     = (float*)carve((size_t)D * 4);
    float* u_b     = (float*)carve((size_t)D * 4);
    float* cst     = (float*)carve(16);
    float* edot_f  = (float*)carve((size_t)E_EDGES * 4);
    float* edot_b  = (float*)carve((size_t)E_EDGES * 4);
    int*   offs    = (int*)carve((size_t)16 * 65537 * 4);
    int*   csr_j   = (int*)carve((size_t)16 * EL * 4);
    float* csr_edot= (float*)carve((size_t)16 * EL * 4);
    int*   rows    = (int*)carve((size_t)16 * 65536 * 4);
    float* msgc    = (float*)carve((size_t)N_NODES * D * 4);   // compacted msg
    float* gi      = (float*)carve((size_t)N_NODES * 384 * 4); // 96 MB
    float* h_fwd   = (float*)carve((size_t)N_NODES * D * 4);
    float* h_cur   = (float*)carve((size_t)N_NODES * D * 4);
    float* qdot    = (float*)carve((size_t)N_NODES * 4);
    float* hdot    = (float*)carve((size_t)N_NODES * 4);

    hipMemsetAsync(counts, 0, zbytes, stream);
    prep_kernel<<<1, 256, 0, stream>>>(We_f, Wa_f, be_f, ba_f, We_b, Wa_b, be_b, ba_b,
                                       u_f, u_b, cst);
    convert_w4<<<dim3(192, 4), 256, 0, stream>>>(Wi_f, Wh_f, Wi_b, Wh_b, W_hi, W_lo);
    count_flags<<<E_EDGES / 256, 256, 0, stream>>>(ei, counts, flag_f, flag_b);
    edot_kernel<<<E_EDGES / 4, 256, 0, stream>>>(ea, u_f, u_b, cst, edot_f, edot_b);
    scan_kernel<<<16, 1024, 0, stream>>>(counts, offs);
    fill_csr<<<2 * E_EDGES / 256, 256, 0, stream>>>(ei, edot_f, edot_b, offs, cursor,
                                                    csr_j, csr_edot);
    compact_kernel<<<16 * 65536 / 256, 256, 0, stream>>>(counts, rows, cnts);

    for (int dir = 0; dir < 2; ++dir) {
        const float* hp   = dir == 0 ? x : h_fwd;
        float*       h    = dir == 0 ? h_fwd : h_cur;
        const u16*   Wihi = W_hi + (size_t)(dir * 2) * 49152;
        const u16*   Wilo = W_lo + (size_t)(dir * 2) * 49152;
        const u16*   Whhi = W_hi + (size_t)(dir * 2 + 1) * 49152;
        const u16*   Whlo = W_lo + (size_t)(dir * 2 + 1) * 49152;
        const float* bi   = dir == 0 ? bi_f : bi_b;
        const float* bh   = dir == 0 ? bh_f : bh_b;
        const float* wa   = dir == 0 ? Wa_f : Wa_b;
        const int*   flag = dir == 0 ? flag_f : flag_b;

        gemm_fused<0><<<512, 512, 0, stream>>>(
            hp, Wihi, Wilo, nullptr, nullptr, bi, bh, wa, flag,
            gi, h, hdot, qdot);

        for (int t = 0; t < LVLS; ++t) {
            int lv = dir == 0 ? t : (LVLS - 1 - t);
            int dl = dir * LVLS + lv;
            attn_msg<<<1024, 256, 0, stream>>>(
                cnts + dl, rows + (size_t)dl * 65536, offs + (size_t)dl * 65537,
                csr_j + (size_t)dl * EL, csr_edot + (size_t)dl * EL,
                qdot, hdot, h, msgc);
            gemm_fused<1><<<512, 512, 0, stream>>>(
                msgc, Whhi, Whlo, cnts + dl, rows + (size_t)dl * 65536,
                nullptr, bh, wa, nullptr, gi, h, hdot, qdot);
        }
    }
    relu_kernel<<<(N_NODES * D) / 1024, 256, 0, stream>>>(h_cur, out);
}

// Round 9
// 2053.671 us; speedup vs baseline: 4.6382x; 4.6382x over previous
//
#include <hip/hip_runtime.h>
#include <cstdint>
#include <cstddef>

constexpr int N_NODES = 65536;
constexpr int D       = 128;
constexpr int E_EDGES = 524288;
constexpr int LVLS    = 8;
constexpr int EL      = E_EDGES / LVLS;   // 65536

typedef unsigned int  u32;
typedef unsigned short u16;
typedef __attribute__((ext_vector_type(8)))  short short8;   // 8 bf16 (4 VGPR)
typedef __attribute__((ext_vector_type(16))) float f32x16;

__device__ __forceinline__ float sigmoidf_(float x) { return 1.0f / (1.0f + expf(-x)); }

__device__ __forceinline__ u32 bf_hi(float f) {           // f32 -> bf16 bits (RNE)
    u32 x = __float_as_uint(f);
    return (x + 0x7fffu + ((x >> 16) & 1u)) >> 16;
}
__device__ __forceinline__ float bf_f(u32 hbits) { return __uint_as_float(hbits << 16); }

// Swizzled byte offset inside a [rows][32 bf16] LDS tile (64B rows).
// XOR of bits 4-5 only: bijective within each 64B row (4x16B slot permute).
__device__ __forceinline__ int swz(int row, int kbyte) {
    return row * 64 + (kbyte ^ ((row & 3) << 4));
}

__device__ __forceinline__ float wave_sum(float v) {
#pragma unroll
    for (int off = 32; off > 0; off >>= 1) v += __shfl_down(v, off, 64);
    return v;
}

// ---------------------------------------------------------------------------
// u_dir[c] = sum_d We[d][c]*wa2[d];  cst = be.wa2 + ba
__global__ __launch_bounds__(256)
void prep_kernel(const float* __restrict__ We_f, const float* __restrict__ Wa_f,
                 const float* __restrict__ be_f, const float* __restrict__ ba_f,
                 const float* __restrict__ We_b, const float* __restrict__ Wa_b,
                 const float* __restrict__ be_b, const float* __restrict__ ba_b,
                 float* __restrict__ u_f, float* __restrict__ u_b, float* __restrict__ cst)
{
    int t = threadIdx.x;
    if (t < 128) {
        float s = 0.f;
        for (int d = 0; d < 128; ++d) s = fmaf(We_f[d * 128 + t], Wa_f[128 + d], s);
        u_f[t] = s;
    } else {
        int c = t - 128;
        float s = 0.f;
        for (int d = 0; d < 128; ++d) s = fmaf(We_b[d * 128 + c], Wa_b[128 + d], s);
        u_b[c] = s;
    }
    if (t == 0) {
        float s = 0.f;
        for (int d = 0; d < 128; ++d) s = fmaf(be_f[d], Wa_f[128 + d], s);
        cst[0] = s + ba_f[0];
    }
    if (t == 255) {
        float s = 0.f;
        for (int d = 0; d < 128; ++d) s = fmaf(be_b[d], Wa_b[128 + d], s);
        cst[1] = s + ba_b[0];
    }
}

// ---------------------------------------------------------------------------
// all 4 weight matrices -> bf16 hi/lo; wsel = blockIdx.y in {WiF,WhF,WiB,WhB}
__global__ __launch_bounds__(256)
void convert_w4(const float* __restrict__ W0, const float* __restrict__ W1,
                const float* __restrict__ W2, const float* __restrict__ W3,
                u16* __restrict__ hi, u16* __restrict__ lo)
{
    const float* Ws[4] = {W0, W1, W2, W3};
    int wsel = blockIdx.y;
    int i = blockIdx.x * 256 + threadIdx.x;        // < 49152
    float v = Ws[wsel][i];
    u32 hb = bf_hi(v);
    hi[wsel * 49152 + i] = (u16)hb;
    lo[wsel * 49152 + i] = (u16)bf_hi(v - bf_f(hb));
}

// ---------------------------------------------------------------------------
__global__ __launch_bounds__(256)
void edot_kernel(const float* __restrict__ ea, const float* __restrict__ u_f,
                 const float* __restrict__ u_b, const float* __restrict__ cst,
                 float* __restrict__ edot_f, float* __restrict__ edot_b)
{
    int wv = threadIdx.x >> 6, lane = threadIdx.x & 63;
    int e = blockIdx.x * 4 + wv;
    if (e >= E_EDGES) return;
    int d = lane << 1;
    float2 v  = *reinterpret_cast<const float2*>(ea + (size_t)e * 128 + d);
    float2 uf = *reinterpret_cast<const float2*>(u_f + d);
    float2 ub = *reinterpret_cast<const float2*>(u_b + d);
    float af = wave_sum(v.x * uf.x + v.y * uf.y);
    float ab = wave_sum(v.x * ub.x + v.y * ub.y);
    if (lane == 0) {
        edot_f[e] = af + cst[0];
        edot_b[e] = ab + cst[1];
    }
}

// ---------------------------------------------------------------------------
// per-(dir,level) target counts + direction flags. dl = dir*8+lvl.
__global__ __launch_bounds__(256)
void count_flags(const int* __restrict__ ei, int* __restrict__ counts,
                 int* __restrict__ flag_f, int* __restrict__ flag_b)
{
    int e = blockIdx.x * 256 + threadIdx.x;
    int lv = e >> 16;
    int s = ei[e], t = ei[E_EDGES + e];
    atomicAdd(&counts[(size_t)lv * 65536 + t], 1);           // fwd: target = dst
    atomicAdd(&counts[(size_t)(8 + lv) * 65536 + s], 1);     // bwd: target = src
    flag_f[t] = 1;
    flag_b[s] = 1;
}

// ---------------------------------------------------------------------------
// Per dl-segment: exclusive scan of counts -> offs[65537], AND compaction of
// nonzero-count nodes -> rows (sorted, deterministic) + cnts[dl]. Zero atomics
// (the R8 compact_kernel's 700K same-cacheline atomics cost 7.5 ms).
__global__ __launch_bounds__(1024)
void scan_compact(const int* __restrict__ counts, int* __restrict__ offs,
                  int* __restrict__ rows, int* __restrict__ cnts)
{
    __shared__ int sbuf[1024];
    __shared__ int nbuf[1024];
    int dl = blockIdx.x;
    const int* c = counts + (size_t)dl * 65536;
    int* o = offs + (size_t)dl * 65537;
    int* rw = rows + (size_t)dl * 65536;
    int t = threadIdx.x;
    int base = t * 64;
    int s = 0, nz = 0;
    for (int k = 0; k < 64; ++k) {
        int cv = c[base + k];
        s += cv;
        nz += (cv > 0);
    }
    sbuf[t] = s;
    nbuf[t] = nz;
    __syncthreads();
    int val = s, nval = nz;
    for (int off = 1; off < 1024; off <<= 1) {
        int add  = (t >= off) ? sbuf[t - off] : 0;
        int nadd = (t >= off) ? nbuf[t - off] : 0;
        __syncthreads();
        val += add;
        nval += nadd;
        sbuf[t] = val;
        nbuf[t] = nval;
        __syncthreads();
    }
    int run  = val - s;    // exclusive prefix of edge counts
    int nrun = nval - nz;  // exclusive prefix of nonzero predicate
    for (int k = 0; k < 64; ++k) {
        int cv = c[base + k];
        o[base + k] = run;
        run += cv;
        if (cv > 0) rw[nrun++] = base + k;
    }
    if (t == 1023) { o[65536] = val; cnts[dl] = nval; }
}

// ---------------------------------------------------------------------------
// fill CSR entries: per edge, slot = dl*EL + offs[i] + cursor++ ; store (j, edot)
__global__ __launch_bounds__(256)
void fill_csr(const int* __restrict__ ei, const float* __restrict__ edot_f,
              const float* __restrict__ edot_b, const int* __restrict__ offs,
              int* __restrict__ cursor, int* __restrict__ csr_j,
              float* __restrict__ csr_edot)
{
    int idx = blockIdx.x * 256 + threadIdx.x;       // < 2E
    int dir = idx >= E_EDGES;
    int ge = dir ? idx - E_EDGES : idx;
    int lv = ge >> 16;
    int dl = dir * 8 + lv;
    int i = dir ? ei[ge] : ei[E_EDGES + ge];
    int j = dir ? ei[E_EDGES + ge] : ei[ge];
    int pos = offs[(size_t)dl * 65537 + i] + atomicAdd(&cursor[(size_t)dl * 65536 + i], 1);
    int slot = dl * EL + pos;
    csr_j[slot] = j;
    csr_edot[slot] = dir ? edot_b[ge] : edot_f[ge];
}

// ---------------------------------------------------------------------------
// wave per target: single-pass softmax-weighted aggregation, compacted output.
// msgc[r] = (sum_e exp(alpha_e) * h[j_e]) / (sum_e exp(alpha_e))
__global__ __launch_bounds__(256)
void attn_msg(const int* __restrict__ pcnt, const int* __restrict__ rows,
              const int* __restrict__ offs, const int* __restrict__ csr_j,
              const float* __restrict__ csr_edot, const float* __restrict__ qdot,
              const float* __restrict__ hdot, const float* __restrict__ h,
              float* __restrict__ msgc)
{
    int cnt = *pcnt;
    int lane = threadIdx.x & 63;
    int wid = (blockIdx.x * 256 + threadIdx.x) >> 6;
    int nw = (gridDim.x * 256) >> 6;
    int d = lane << 1;
    for (int r = wid; r < cnt; r += nw) {
        int i = rows[r];
        int o0 = offs[i], o1 = offs[i + 1];
        float qi = qdot[i];
        float den = 0.f, ax = 0.f, ay = 0.f;
        for (int e = o0; e < o1; ++e) {
            int j = csr_j[e];
            float ex = expf(qi + hdot[j] + csr_edot[e]);
            float2 hv = *reinterpret_cast<const float2*>(h + (size_t)j * 128 + d);
            den += ex;
            ax = fmaf(ex, hv.x, ax);
            ay = fmaf(ex, hv.y, ay);
        }
        float inv = 1.f / den;
        *reinterpret_cast<float2*>(msgc + (size_t)r * 128 + d) = make_float2(ax * inv, ay * inv);
    }
}

// ---------------------------------------------------------------------------
// Fused split-bf16 MFMA GEMM (C = A @ W^T, K=128, Ncols=384) + GRU epilogue.
// MODE 0: A=h_prev [65536,128], W=Wi. gi(+bi) for flagged, h-init for roots,
//         qdot, hdot.
// MODE 1: A=msgc [cnt,128] DENSE, W=Wh. Full GRU (hidden=msgc row), scatter
//         h/hdot via rows[].
template<int MODE>
__global__ __launch_bounds__(512, 2)
void gemm_fused(const float* __restrict__ A,
                const u16* __restrict__ Whi, const u16* __restrict__ Wlo,
                const int* __restrict__ pcnt, const int* __restrict__ rows,
                const float* __restrict__ bi,
                const float* __restrict__ bh,
                const float* __restrict__ wa,
                const int* __restrict__ flag,
                float* __restrict__ gi,
                float* __restrict__ h,
                float* __restrict__ hdot, float* __restrict__ qdot)
{
    __shared__ __align__(16) unsigned char smem[16384 + 49152 + 4096 + 512];
    unsigned char* As = smem;               // [2 halves][128][32 bf16] swizzled
    unsigned char* Bs = smem + 16384;       // [2 halves][384][32 bf16] swizzled
    float* red   = (float*)(smem + 16384 + 49152);      // [128][4] (+[128][4] qdot)
    int* rowsLds = (int*)(smem + 16384 + 49152 + 4096); // [128]

    const int tid = threadIdx.x;
    int cnt;
    if constexpr (MODE == 0) cnt = N_NODES; else cnt = *pcnt;
    const int row0 = blockIdx.x * 128;
    if (row0 >= cnt) return;

    if constexpr (MODE == 1) {
        if (tid < 128) rowsLds[tid] = rows[row0 + tid];   // beyond-cnt: garbage, masked later
        __syncthreads();
    }

    f32x16 acc[2][3];
#pragma unroll
    for (int mt = 0; mt < 2; ++mt)
#pragma unroll
        for (int g = 0; g < 3; ++g) acc[mt][g] = (f32x16)0.0f;

    const int lane = tid & 63, wv = tid >> 6;
    const int q = wv & 3, mh = wv >> 2;
    const int l31 = lane & 31, l5 = lane >> 5;

    for (int k0 = 0; k0 < 128; k0 += 32) {
        // ---- stage A (f32 -> bf16 hi/lo): 128 rows x 32 k (dense in both modes)
#pragma unroll
        for (int p = 0; p < 2; ++p) {
            int idx = tid + p * 512;
            int rw = idx >> 3, kf = (idx & 7) << 2;
            float4 v = *reinterpret_cast<const float4*>(A + (size_t)(row0 + rw) * 128 + k0 + kf);
            u32 h0 = bf_hi(v.x), h1 = bf_hi(v.y), h2 = bf_hi(v.z), h3 = bf_hi(v.w);
            u32 l0 = bf_hi(v.x - bf_f(h0)), l1 = bf_hi(v.y - bf_f(h1));
            u32 l2 = bf_hi(v.z - bf_f(h2)), l3 = bf_hi(v.w - bf_f(h3));
            int off = swz(rw, kf * 2);
            *reinterpret_cast<uint2*>(As + off)        = make_uint2(h0 | (h1 << 16), h2 | (h3 << 16));
            *reinterpret_cast<uint2*>(As + 8192 + off) = make_uint2(l0 | (l1 << 16), l2 | (l3 << 16));
        }
        // ---- stage B (preconverted bf16 hi/lo): 384 rows x 32 k x 2 halves
#pragma unroll
        for (int p = 0; p < 6; ++p) {
            int c = tid + p * 512;
            int hf = c & 1, cc = c >> 1;
            int rw = cc >> 2, kc = cc & 3;
            const u16* src = hf ? Wlo : Whi;
            uint4 v = *reinterpret_cast<const uint4*>(src + (size_t)rw * 128 + k0 + kc * 8);
            *reinterpret_cast<uint4*>(Bs + hf * 24576 + swz(rw, kc * 16)) = v;
        }
        __syncthreads();
        // ---- MFMA
#pragma unroll
        for (int kh = 0; kh < 2; ++kh) {
            short8 a[2][2], b[3][2];
#pragma unroll
            for (int mt = 0; mt < 2; ++mt)
#pragma unroll
                for (int hf = 0; hf < 2; ++hf)
                    a[mt][hf] = *reinterpret_cast<const short8*>(
                        As + hf * 8192 + swz(mh * 64 + mt * 32 + l31, kh * 32 + l5 * 16));
#pragma unroll
            for (int g = 0; g < 3; ++g)
#pragma unroll
                for (int hf = 0; hf < 2; ++hf)
                    b[g][hf] = *reinterpret_cast<const short8*>(
                        Bs + hf * 24576 + swz(q * 32 + g * 128 + l31, kh * 32 + l5 * 16));
#pragma unroll
            for (int mt = 0; mt < 2; ++mt)
#pragma unroll
                for (int g = 0; g < 3; ++g) {
                    acc[mt][g] = __builtin_amdgcn_mfma_f32_32x32x16_bf16(a[mt][0], b[g][0], acc[mt][g], 0, 0, 0);
                    acc[mt][g] = __builtin_amdgcn_mfma_f32_32x32x16_bf16(a[mt][0], b[g][1], acc[mt][g], 0, 0, 0);
                    acc[mt][g] = __builtin_amdgcn_mfma_f32_32x32x16_bf16(a[mt][1], b[g][0], acc[mt][g], 0, 0, 0);
                }
        }
        __syncthreads();
    }

    // ---- epilogue
    const int d = q * 32 + l31;
    const float wa2d = wa[128 + d];
    const float bh0 = bh[d], bh1 = bh[d + 128], bh2 = bh[d + 256];
    float bi0 = 0.f, bi1 = 0.f, bi2 = 0.f, wa1d = 0.f;
    if constexpr (MODE == 0) {
        bi0 = bi[d]; bi1 = bi[d + 128]; bi2 = bi[d + 256]; wa1d = wa[d];
    }

#pragma unroll
    for (int mt = 0; mt < 2; ++mt)
#pragma unroll
        for (int rg = 0; rg < 16; ++rg) {
            int rl = mh * 64 + mt * 32 + (rg & 3) + ((rg >> 2) << 3) + (l5 << 2);
            int gr = row0 + rl;
            float hv = 0.f, pq = 0.f;
            if constexpr (MODE == 0) {
                int n = gr;
                int fl = flag[n];
                float g0 = acc[mt][0][rg] + bi0;
                float g1 = acc[mt][1][rg] + bi1;
                float g2 = acc[mt][2][rg] + bi2;
                if (fl) {
                    gi[(size_t)n * 384 + d]       = g0;
                    gi[(size_t)n * 384 + d + 128] = g1;
                    gi[(size_t)n * 384 + d + 256] = g2;
                } else {
                    float rr = sigmoidf_(g0 + bh0);
                    float zz = sigmoidf_(g1 + bh1);
                    float nn = tanhf(g2 + rr * bh2);
                    hv = (1.f - zz) * nn;          // hidden = 0 for roots
                }
                h[(size_t)n * 128 + d] = hv;
                pq = A[(size_t)n * 128 + d] * wa1d;  // A == h_prev
            } else {
                bool ok = gr < cnt;
                int n = ok ? rowsLds[rl] : 0;
                const float* gin = gi + (size_t)n * 384;
                float mval = A[(size_t)gr * 128 + d];   // hidden = msg (dense row)
                float rr = sigmoidf_(gin[d]       + acc[mt][0][rg] + bh0);
                float zz = sigmoidf_(gin[d + 128] + acc[mt][1][rg] + bh1);
                float nn = tanhf(gin[d + 256] + rr * (acc[mt][2][rg] + bh2));
                hv = (1.f - zz) * nn + zz * mval;
                if (ok) h[(size_t)n * 128 + d] = hv;
            }
            float pd = hv * wa2d;
#pragma unroll
            for (int o = 1; o < 32; o <<= 1) pd += __shfl_xor(pd, o, 64);
            if constexpr (MODE == 0) {
#pragma unroll
                for (int o = 1; o < 32; o <<= 1) pq += __shfl_xor(pq, o, 64);
            }
            if (l31 == 0) {
                red[rl * 4 + q] = pd;
                if constexpr (MODE == 0) red[512 + rl * 4 + q] = pq;
            }
        }
    __syncthreads();
    if (tid < 128) {
        int gr = row0 + tid;
        if (gr < cnt) {
            int n;
            if constexpr (MODE == 0) n = gr; else n = rowsLds[tid];
            hdot[n] = red[tid * 4] + red[tid * 4 + 1] + red[tid * 4 + 2] + red[tid * 4 + 3];
            if constexpr (MODE == 0)
                qdot[n] = red[512 + tid * 4] + red[512 + tid * 4 + 1] +
                          red[512 + tid * 4 + 2] + red[512 + tid * 4 + 3];
        }
    }
}

// ---------------------------------------------------------------------------
__global__ __launch_bounds__(256)
void relu_kernel(const float* __restrict__ h, float* __restrict__ out)
{
    int idx = (blockIdx.x * 256 + threadIdx.x) * 4;
    float4 v = *reinterpret_cast<const float4*>(h + idx);
    v.x = fmaxf(v.x, 0.f); v.y = fmaxf(v.y, 0.f);
    v.z = fmaxf(v.z, 0.f); v.w = fmaxf(v.w, 0.f);
    *reinterpret_cast<float4*>(out + idx) = v;
}

// ---------------------------------------------------------------------------
extern "C" void kernel_launch(void* const* d_in, const int* in_sizes, int n_in,
                              void* d_out, int out_size, void* d_ws, size_t ws_size,
                              hipStream_t stream)
{
    (void)in_sizes; (void)n_in; (void)out_size; (void)ws_size;

    const float* x    = (const float*)d_in[0];
    const int*   ei   = (const int*)d_in[1];
    const float* ea   = (const float*)d_in[2];
    const float* We_f = (const float*)d_in[4];
    const float* be_f = (const float*)d_in[5];
    const float* Wa_f = (const float*)d_in[6];
    const float* ba_f = (const float*)d_in[7];
    const float* Wi_f = (const float*)d_in[8];
    const float* Wh_f = (const float*)d_in[9];
    const float* bi_f = (const float*)d_in[10];
    const float* bh_f = (const float*)d_in[11];
    const float* We_b = (const float*)d_in[12];
    const float* be_b = (const float*)d_in[13];
    const float* Wa_b = (const float*)d_in[14];
    const float* ba_b = (const float*)d_in[15];
    const float* Wi_b = (const float*)d_in[16];
    const float* Wh_b = (const float*)d_in[17];
    const float* bi_b = (const float*)d_in[18];
    const float* bh_b = (const float*)d_in[19];
    float* out = (float*)d_out;

    char* p = (char*)d_ws;
    auto carve = [&](size_t bytes) -> char* {
        char* r = p;
        p += (bytes + 255) & ~(size_t)255;
        return r;
    };
    // ---- zeroed region (contiguous, one memset per launch) ----
    int*   counts  = (int*)carve((size_t)16 * 65536 * 4);      // [dir*8+lvl][node]
    int*   cursor  = (int*)carve((size_t)16 * 65536 * 4);
    int*   flag_f  = (int*)carve((size_t)N_NODES * 4);
    int*   flag_b  = (int*)carve((size_t)N_NODES * 4);
    size_t zbytes  = (size_t)((char*)flag_b - (char*)counts) + (size_t)N_NODES * 4;
    // ---- rest (fully overwritten each launch before use) ----
    int*   cnts    = (int*)carve(256);                         // 16 used (scan-written)
    u16*   W_hi    = (u16*)carve((size_t)4 * 49152 * 2);       // WiF,WhF,WiB,WhB
    u16*   W_lo    = (u16*)carve((size_t)4 * 49152 * 2);
    float* u_f     = (float*)carve((size_t)D * 4);
    float* u_b     = (float*)carve((size_t)D * 4);
    float* cst     = (float*)carve(16);
    float* edot_f  = (float*)carve((size_t)E_EDGES * 4);
    float* edot_b  = (float*)carve((size_t)E_EDGES * 4);
    int*   offs    = (int*)carve((size_t)16 * 65537 * 4);
    int*   csr_j   = (int*)carve((size_t)16 * EL * 4);
    float* csr_edot= (float*)carve((size_t)16 * EL * 4);
    int*   rows    = (int*)carve((size_t)16 * 65536 * 4);
    float* msgc    = (float*)carve((size_t)N_NODES * D * 4);   // compacted msg
    float* gi      = (float*)carve((size_t)N_NODES * 384 * 4); // 96 MB
    float* h_fwd   = (float*)carve((size_t)N_NODES * D * 4);
    float* h_cur   = (float*)carve((size_t)N_NODES * D * 4);
    float* qdot    = (float*)carve((size_t)N_NODES * 4);
    float* hdot    = (float*)carve((size_t)N_NODES * 4);

    hipMemsetAsync(counts, 0, zbytes, stream);
    prep_kernel<<<1, 256, 0, stream>>>(We_f, Wa_f, be_f, ba_f, We_b, Wa_b, be_b, ba_b,
                                       u_f, u_b, cst);
    convert_w4<<<dim3(192, 4), 256, 0, stream>>>(Wi_f, Wh_f, Wi_b, Wh_b, W_hi, W_lo);
    count_flags<<<E_EDGES / 256, 256, 0, stream>>>(ei, counts, flag_f, flag_b);
    edot_kernel<<<E_EDGES / 4, 256, 0, stream>>>(ea, u_f, u_b, cst, edot_f, edot_b);
    scan_compact<<<16, 1024, 0, stream>>>(counts, offs, rows, cnts);
    fill_csr<<<2 * E_EDGES / 256, 256, 0, stream>>>(ei, edot_f, edot_b, offs, cursor,
                                                    csr_j, csr_edot);

    for (int dir = 0; dir < 2; ++dir) {
        const float* hp   = dir == 0 ? x : h_fwd;
        float*       h    = dir == 0 ? h_fwd : h_cur;
        const u16*   Wihi = W_hi + (size_t)(dir * 2) * 49152;
        const u16*   Wilo = W_lo + (size_t)(dir * 2) * 49152;
        const u16*   Whhi = W_hi + (size_t)(dir * 2 + 1) * 49152;
        const u16*   Whlo = W_lo + (size_t)(dir * 2 + 1) * 49152;
        const float* bi   = dir == 0 ? bi_f : bi_b;
        const float* bh   = dir == 0 ? bh_f : bh_b;
        const float* wa   = dir == 0 ? Wa_f : Wa_b;
        const int*   flag = dir == 0 ? flag_f : flag_b;

        gemm_fused<0><<<512, 512, 0, stream>>>(
            hp, Wihi, Wilo, nullptr, nullptr, bi, bh, wa, flag,
            gi, h, hdot, qdot);

        for (int t = 0; t < LVLS; ++t) {
            int lv = dir == 0 ? t : (LVLS - 1 - t);
            int dl = dir * LVLS + lv;
            attn_msg<<<1024, 256, 0, stream>>>(
                cnts + dl, rows + (size_t)dl * 65536, offs + (size_t)dl * 65537,
                csr_j + (size_t)dl * EL, csr_edot + (size_t)dl * EL,
                qdot, hdot, h, msgc);
            gemm_fused<1><<<512, 512, 0, stream>>>(
                msgc, Whhi, Whlo, cnts + dl, rows + (size_t)dl * 65536,
                nullptr, bh, wa, nullptr, gi, h, hdot, qdot);
        }
    }
    relu_kernel<<<(N_NODES * D) / 1024, 256, 0, stream>>>(h_cur, out);
}

// Round 10
// 1821.020 us; speedup vs baseline: 5.2308x; 1.1278x over previous
//
#include <hip/hip_runtime.h>
#include <cstdint>
#include <cstddef>

constexpr int N_NODES = 65536;
constexpr int D       = 128;
constexpr int E_EDGES = 524288;
constexpr int LVLS    = 8;
constexpr int EL      = E_EDGES / LVLS;   // 65536
constexpr int OSTR    = 65540;            // offs segment stride (16B-aligned)

typedef unsigned int  u32;
typedef unsigned short u16;
typedef __attribute__((ext_vector_type(8)))  short short8;   // 8 bf16 (4 VGPR)
typedef __attribute__((ext_vector_type(16))) float f32x16;

__device__ __forceinline__ float sigmoidf_(float x) { return 1.0f / (1.0f + expf(-x)); }

__device__ __forceinline__ u32 bf_hi(float f) {           // f32 -> bf16 bits (RNE)
    u32 x = __float_as_uint(f);
    return (x + 0x7fffu + ((x >> 16) & 1u)) >> 16;
}
__device__ __forceinline__ float bf_f(u32 hbits) { return __uint_as_float(hbits << 16); }

// Swizzled byte offset inside a [rows][32 bf16] LDS tile (64B rows).
// XOR of bits 4-5 only: bijective within each 64B row (4x16B slot permute).
__device__ __forceinline__ int swz(int row, int kbyte) {
    return row * 64 + (kbyte ^ ((row & 3) << 4));
}

__device__ __forceinline__ float wave_sum(float v) {
#pragma unroll
    for (int off = 32; off > 0; off >>= 1) v += __shfl_down(v, off, 64);
    return v;
}

// ---------------------------------------------------------------------------
// u_dir[c] = sum_d We[d][c]*wa2[d];  cst = be.wa2 + ba
__global__ __launch_bounds__(256)
void prep_kernel(const float* __restrict__ We_f, const float* __restrict__ Wa_f,
                 const float* __restrict__ be_f, const float* __restrict__ ba_f,
                 const float* __restrict__ We_b, const float* __restrict__ Wa_b,
                 const float* __restrict__ be_b, const float* __restrict__ ba_b,
                 float* __restrict__ u_f, float* __restrict__ u_b, float* __restrict__ cst)
{
    int t = threadIdx.x;
    if (t < 128) {
        float s = 0.f;
        for (int d = 0; d < 128; ++d) s = fmaf(We_f[d * 128 + t], Wa_f[128 + d], s);
        u_f[t] = s;
    } else {
        int c = t - 128;
        float s = 0.f;
        for (int d = 0; d < 128; ++d) s = fmaf(We_b[d * 128 + c], Wa_b[128 + d], s);
        u_b[c] = s;
    }
    if (t == 0) {
        float s = 0.f;
        for (int d = 0; d < 128; ++d) s = fmaf(be_f[d], Wa_f[128 + d], s);
        cst[0] = s + ba_f[0];
    }
    if (t == 255) {
        float s = 0.f;
        for (int d = 0; d < 128; ++d) s = fmaf(be_b[d], Wa_b[128 + d], s);
        cst[1] = s + ba_b[0];
    }
}

// ---------------------------------------------------------------------------
// all 4 weight matrices -> bf16 hi/lo; wsel = blockIdx.y in {WiF,WhF,WiB,WhB}
__global__ __launch_bounds__(256)
void convert_w4(const float* __restrict__ W0, const float* __restrict__ W1,
                const float* __restrict__ W2, const float* __restrict__ W3,
                u16* __restrict__ hi, u16* __restrict__ lo)
{
    const float* Ws[4] = {W0, W1, W2, W3};
    int wsel = blockIdx.y;
    int i = blockIdx.x * 256 + threadIdx.x;        // < 49152
    float v = Ws[wsel][i];
    u32 hb = bf_hi(v);
    hi[wsel * 49152 + i] = (u16)hb;
    lo[wsel * 49152 + i] = (u16)bf_hi(v - bf_f(hb));
}

// ---------------------------------------------------------------------------
__global__ __launch_bounds__(256)
void edot_kernel(const float* __restrict__ ea, const float* __restrict__ u_f,
                 const float* __restrict__ u_b, const float* __restrict__ cst,
                 float* __restrict__ edot_f, float* __restrict__ edot_b)
{
    int wv = threadIdx.x >> 6, lane = threadIdx.x & 63;
    int e = blockIdx.x * 4 + wv;
    if (e >= E_EDGES) return;
    int d = lane << 1;
    float2 v  = *reinterpret_cast<const float2*>(ea + (size_t)e * 128 + d);
    float2 uf = *reinterpret_cast<const float2*>(u_f + d);
    float2 ub = *reinterpret_cast<const float2*>(u_b + d);
    float af = wave_sum(v.x * uf.x + v.y * uf.y);
    float ab = wave_sum(v.x * ub.x + v.y * ub.y);
    if (lane == 0) {
        edot_f[e] = af + cst[0];
        edot_b[e] = ab + cst[1];
    }
}

// ---------------------------------------------------------------------------
// per-(dir,level) target counts + direction flags. dl = dir*8+lvl.
__global__ __launch_bounds__(256)
void count_flags(const int* __restrict__ ei, int* __restrict__ counts,
                 int* __restrict__ flag_f, int* __restrict__ flag_b)
{
    int e = blockIdx.x * 256 + threadIdx.x;
    int lv = e >> 16;
    int s = ei[e], t = ei[E_EDGES + e];
    atomicAdd(&counts[(size_t)lv * 65536 + t], 1);           // fwd: target = dst
    atomicAdd(&counts[(size_t)(8 + lv) * 65536 + s], 1);     // bwd: target = src
    flag_f[t] = 1;
    flag_b[s] = 1;
}

// ---------------------------------------------------------------------------
// Per dl-segment: exclusive scan of counts -> offs[OSTR], AND compaction of
// nonzero-count nodes -> rows (sorted, deterministic) + cnts[dl]. No atomics.
// int4-vectorized reads/writes.
__global__ __launch_bounds__(1024)
void scan_compact(const int* __restrict__ counts, int* __restrict__ offs,
                  int* __restrict__ rows, int* __restrict__ cnts)
{
    __shared__ int sbuf[1024];
    __shared__ int nbuf[1024];
    int dl = blockIdx.x;
    const int4* c4 = reinterpret_cast<const int4*>(counts + (size_t)dl * 65536);
    int* o = offs + (size_t)dl * OSTR;
    int* rw = rows + (size_t)dl * 65536;
    int t = threadIdx.x;
    int cv[64];
#pragma unroll 4
    for (int k4 = 0; k4 < 16; ++k4) {
        int4 v = c4[t * 16 + k4];
        cv[k4 * 4 + 0] = v.x; cv[k4 * 4 + 1] = v.y;
        cv[k4 * 4 + 2] = v.z; cv[k4 * 4 + 3] = v.w;
    }
    int s = 0, nz = 0;
#pragma unroll
    for (int k = 0; k < 64; ++k) { s += cv[k]; nz += (cv[k] > 0); }
    sbuf[t] = s;
    nbuf[t] = nz;
    __syncthreads();
    int val = s, nval = nz;
    for (int off = 1; off < 1024; off <<= 1) {
        int add  = (t >= off) ? sbuf[t - off] : 0;
        int nadd = (t >= off) ? nbuf[t - off] : 0;
        __syncthreads();
        val += add;
        nval += nadd;
        sbuf[t] = val;
        nbuf[t] = nval;
        __syncthreads();
    }
    int run  = val - s;    // exclusive prefix of edge counts
    int nrun = nval - nz;  // exclusive prefix of nonzero predicate
    int base = t * 64;
    int4* o4 = reinterpret_cast<int4*>(o + base);
#pragma unroll 4
    for (int k4 = 0; k4 < 16; ++k4) {
        int4 ov;
        ov.x = run; run += cv[k4 * 4 + 0];
        ov.y = run; run += cv[k4 * 4 + 1];
        ov.z = run; run += cv[k4 * 4 + 2];
        ov.w = run; run += cv[k4 * 4 + 3];
        o4[k4] = ov;
#pragma unroll
        for (int q = 0; q < 4; ++q)
            if (cv[k4 * 4 + q] > 0) rw[nrun++] = base + k4 * 4 + q;
    }
    if (t == 1023) { o[65536] = val; cnts[dl] = nval; }
}

// ---------------------------------------------------------------------------
// fill CSR entries: per edge, slot = dl*EL + offs[i] + cursor++ ; store {j, edot}
__global__ __launch_bounds__(256)
void fill_csr(const int* __restrict__ ei, const float* __restrict__ edot_f,
              const float* __restrict__ edot_b, const int* __restrict__ offs,
              int* __restrict__ cursor, int2* __restrict__ csr)
{
    int idx = blockIdx.x * 256 + threadIdx.x;       // < 2E
    int dir = idx >= E_EDGES;
    int ge = dir ? idx - E_EDGES : idx;
    int lv = ge >> 16;
    int dl = dir * 8 + lv;
    int i = dir ? ei[ge] : ei[E_EDGES + ge];
    int j = dir ? ei[E_EDGES + ge] : ei[ge];
    int pos = offs[(size_t)dl * OSTR + i] + atomicAdd(&cursor[(size_t)dl * 65536 + i], 1);
    int2 v;
    v.x = j;
    v.y = __float_as_int(dir ? edot_b[ge] : edot_f[ge]);
    csr[(size_t)dl * EL + pos] = v;
}

// ---------------------------------------------------------------------------
// Per direction init: qdot[n] = hp[n].wa1 for ALL n; for roots (flag==0):
// h = (1-z)*tanh(...) exact f32, hdot = h.wa2; non-roots: hdot = 0
// (h zeroed by launch memset). Wave per node.
__global__ __launch_bounds__(256)
void root_init(const float* __restrict__ hp, const int* __restrict__ flag,
               const float* __restrict__ Wi, const float* __restrict__ bi,
               const float* __restrict__ bh, const float* __restrict__ wa,
               float* __restrict__ h, float* __restrict__ qdot,
               float* __restrict__ hdot)
{
    int wv = threadIdx.x >> 6, lane = threadIdx.x & 63;
    int n = blockIdx.x * 4 + wv;
    int d = lane << 1;
    const float* hprow = hp + (size_t)n * 128;
    float2 hpv = *reinterpret_cast<const float2*>(hprow + d);
    float qd = wave_sum(hpv.x * wa[d] + hpv.y * wa[d + 1]);
    if (lane == 0) qdot[n] = qd;
    bool root = (flag[n] == 0);
    float hv[2] = {0.f, 0.f};
    if (root) {   // ~e^-8 of nodes; exact f32 path, re-reads row from L1
#pragma unroll
        for (int q = 0; q < 2; ++q) {
            int dd = d + q;
            float g0 = bi[dd], g1 = bi[dd + 128], g2 = bi[dd + 256];
            for (int k = 0; k < 128; ++k) {
                float a = hprow[k];
                g0 = fmaf(a, Wi[(size_t)dd * 128 + k], g0);
                g1 = fmaf(a, Wi[(size_t)(dd + 128) * 128 + k], g1);
                g2 = fmaf(a, Wi[(size_t)(dd + 256) * 128 + k], g2);
            }
            float rr = sigmoidf_(g0 + bh[dd]);
            float zz = sigmoidf_(g1 + bh[dd + 128]);
            float nn = tanhf(g2 + rr * bh[dd + 256]);
            hv[q] = (1.f - zz) * nn;            // hidden = 0 for roots
        }
        *reinterpret_cast<float2*>(h + (size_t)n * 128 + d) = make_float2(hv[0], hv[1]);
    }
    float hd = wave_sum(hv[0] * wa[128 + d] + hv[1] * wa[128 + d + 1]);
    if (lane == 0) hdot[n] = root ? hd : 0.f;
}

// ---------------------------------------------------------------------------
// Half-wave (32 lanes) per target: single-pass softmax-weighted aggregation.
// msgc[r] = (sum_e exp(alpha_e) * h[j_e]) / (sum_e exp(alpha_e))
__global__ __launch_bounds__(256)
void attn_msg(const int* __restrict__ pcnt, const int* __restrict__ rows,
              const int* __restrict__ offs, const int2* __restrict__ csr,
              const float* __restrict__ qdot, const float* __restrict__ hdot,
              const float* __restrict__ h, float* __restrict__ msgc)
{
    int cnt = *pcnt;
    int l31 = threadIdx.x & 31;
    int hid = (blockIdx.x * 256 + threadIdx.x) >> 5;
    int nh = (gridDim.x * 256) >> 5;
    int d4 = l31 << 2;
    for (int r = hid; r < cnt; r += nh) {
        int i = rows[r];
        int o0 = offs[i], o1 = offs[i + 1];
        float qi = qdot[i];
        float den = 0.f;
        float4 acc = make_float4(0.f, 0.f, 0.f, 0.f);
        for (int e = o0; e < o1; ++e) {
            int2 je = csr[e];
            float ex = expf(qi + hdot[je.x] + __int_as_float(je.y));
            float4 hv = *reinterpret_cast<const float4*>(h + (size_t)je.x * 128 + d4);
            den += ex;
            acc.x = fmaf(ex, hv.x, acc.x);
            acc.y = fmaf(ex, hv.y, acc.y);
            acc.z = fmaf(ex, hv.z, acc.z);
            acc.w = fmaf(ex, hv.w, acc.w);
        }
        float inv = 1.f / den;
        *reinterpret_cast<float4*>(msgc + (size_t)r * 128 + d4) =
            make_float4(acc.x * inv, acc.y * inv, acc.z * inv, acc.w * inv);
    }
}

// ---------------------------------------------------------------------------
// Dual-phase split-bf16 MFMA GEMM + GRU epilogue (per level).
// Phase A: acc  = msgc[dense rows] @ Wh^T   (gh; gh_n stashed, slice zeroed)
// Phase B: acc += hp[gathered rows] @ Wi^T  (r/z get gi+gh; n-slice = gi_n)
// Epilogue: r=sig(acc0+bi0+bh0), z=sig(acc1+bi1+bh1),
//           n=tanh(acc2+bi2 + r*(ghn+bh2)), h=(1-z)*n+z*msg; hdot=h.wa2.
// Block: 128 rows x 384 cols, 512 thr = 8 waves (q=w&3 col slice, mh=w>>2).
__global__ __launch_bounds__(512, 1)
void gemm_gru(const float* __restrict__ msgc, const float* __restrict__ hp,
              const u16* __restrict__ Whhi, const u16* __restrict__ Whlo,
              const u16* __restrict__ Wihi, const u16* __restrict__ Wilo,
              const int* __restrict__ pcnt, const int* __restrict__ rows,
              const float* __restrict__ bi, const float* __restrict__ bh,
              const float* __restrict__ wa,
              float* __restrict__ h, float* __restrict__ hdot)
{
    __shared__ __align__(16) unsigned char smem[16384 + 49152 + 2048 + 512];
    unsigned char* As = smem;               // [2 halves][128][32 bf16] swizzled
    unsigned char* Bs = smem + 16384;       // [2 halves][384][32 bf16] swizzled
    float* red   = (float*)(smem + 16384 + 49152);      // [128][4]
    int* rowsLds = (int*)(smem + 16384 + 49152 + 2048); // [128]

    const int tid = threadIdx.x;
    const int cnt = *pcnt;
    const int row0 = blockIdx.x * 128;
    if (row0 >= cnt) return;

    if (tid < 128) {
        int gr = row0 + tid;
        rowsLds[tid] = (gr < cnt) ? rows[gr] : 0;   // clamp: stale rows beyond cnt are garbage
    }
    __syncthreads();

    f32x16 acc[2][3];
#pragma unroll
    for (int mt = 0; mt < 2; ++mt)
#pragma unroll
        for (int g = 0; g < 3; ++g) acc[mt][g] = (f32x16)0.0f;
    f32x16 ghn[2];

    const int lane = tid & 63, wv = tid >> 6;
    const int q = wv & 3, mh = wv >> 2;
    const int l31 = lane & 31, l5 = lane >> 5;

#pragma unroll
    for (int ph = 0; ph < 2; ++ph) {
        const float* Asrc = ph ? hp : msgc;
        const u16* Bhi = ph ? Wihi : Whhi;
        const u16* Blo = ph ? Wilo : Whlo;
        for (int k0 = 0; k0 < 128; k0 += 32) {
            // ---- stage A (f32 -> bf16 hi/lo): 128 rows x 32 k
#pragma unroll
            for (int p = 0; p < 2; ++p) {
                int idx = tid + p * 512;
                int rw = idx >> 3, kf = (idx & 7) << 2;
                int arow = ph ? rowsLds[rw] : (row0 + rw);
                float4 v = *reinterpret_cast<const float4*>(Asrc + (size_t)arow * 128 + k0 + kf);
                u32 h0 = bf_hi(v.x), h1 = bf_hi(v.y), h2 = bf_hi(v.z), h3 = bf_hi(v.w);
                u32 l0 = bf_hi(v.x - bf_f(h0)), l1 = bf_hi(v.y - bf_f(h1));
                u32 l2 = bf_hi(v.z - bf_f(h2)), l3 = bf_hi(v.w - bf_f(h3));
                int off = swz(rw, kf * 2);
                *reinterpret_cast<uint2*>(As + off)        = make_uint2(h0 | (h1 << 16), h2 | (h3 << 16));
                *reinterpret_cast<uint2*>(As + 8192 + off) = make_uint2(l0 | (l1 << 16), l2 | (l3 << 16));
            }
            // ---- stage B (preconverted bf16 hi/lo): 384 rows x 32 k x 2 halves
#pragma unroll
            for (int p = 0; p < 6; ++p) {
                int c = tid + p * 512;
                int hf = c & 1, cc = c >> 1;
                int rw = cc >> 2, kc = cc & 3;
                const u16* src = hf ? Blo : Bhi;
                uint4 v = *reinterpret_cast<const uint4*>(src + (size_t)rw * 128 + k0 + kc * 8);
                *reinterpret_cast<uint4*>(Bs + hf * 24576 + swz(rw, kc * 16)) = v;
            }
            __syncthreads();
            // ---- MFMA (3-term split: Ah*Bh + Ah*Bl + Al*Bh)
#pragma unroll
            for (int kh = 0; kh < 2; ++kh) {
                short8 a[2][2], b[3][2];
#pragma unroll
                for (int mt = 0; mt < 2; ++mt)
#pragma unroll
                    for (int hf = 0; hf < 2; ++hf)
                        a[mt][hf] = *reinterpret_cast<const short8*>(
                            As + hf * 8192 + swz(mh * 64 + mt * 32 + l31, kh * 32 + l5 * 16));
#pragma unroll
                for (int g = 0; g < 3; ++g)
#pragma unroll
                    for (int hf = 0; hf < 2; ++hf)
                        b[g][hf] = *reinterpret_cast<const short8*>(
                            Bs + hf * 24576 + swz(q * 32 + g * 128 + l31, kh * 32 + l5 * 16));
#pragma unroll
                for (int mt = 0; mt < 2; ++mt)
#pragma unroll
                    for (int g = 0; g < 3; ++g) {
                        acc[mt][g] = __builtin_amdgcn_mfma_f32_32x32x16_bf16(a[mt][0], b[g][0], acc[mt][g], 0, 0, 0);
                        acc[mt][g] = __builtin_amdgcn_mfma_f32_32x32x16_bf16(a[mt][0], b[g][1], acc[mt][g], 0, 0, 0);
                        acc[mt][g] = __builtin_amdgcn_mfma_f32_32x32x16_bf16(a[mt][1], b[g][0], acc[mt][g], 0, 0, 0);
                    }
            }
            __syncthreads();
        }
        if (ph == 0) {                       // stash gh_n, zero its slice
            ghn[0] = acc[0][2];
            ghn[1] = acc[1][2];
            acc[0][2] = (f32x16)0.0f;
            acc[1][2] = (f32x16)0.0f;
        }
    }

    // ---- epilogue
    const int d = q * 32 + l31;
    const float wa2d = wa[128 + d];
    const float bi0 = bi[d], bi1 = bi[d + 128], bi2 = bi[d + 256];
    const float bh0 = bh[d], bh1 = bh[d + 128], bh2 = bh[d + 256];

#pragma unroll
    for (int mt = 0; mt < 2; ++mt)
#pragma unroll
        for (int rg = 0; rg < 16; ++rg) {
            int rl = mh * 64 + mt * 32 + (rg & 3) + ((rg >> 2) << 3) + (l5 << 2);
            int gr = row0 + rl;
            bool ok = gr < cnt;
            int n = rowsLds[rl];
            float mval = msgc[(size_t)gr * 128 + d];   // dense; gr < 65536 always
            float rr = sigmoidf_(acc[mt][0][rg] + bi0 + bh0);
            float zz = sigmoidf_(acc[mt][1][rg] + bi1 + bh1);
            float nn = tanhf(acc[mt][2][rg] + bi2 + rr * (ghn[mt][rg] + bh2));
            float hv = (1.f - zz) * nn + zz * mval;    // hidden = msg
            if (ok) h[(size_t)n * 128 + d] = hv;
            float pd = hv * wa2d;
#pragma unroll
            for (int o = 1; o < 32; o <<= 1) pd += __shfl_xor(pd, o, 64);
            if (l31 == 0) red[rl * 4 + q] = pd;
        }
    __syncthreads();
    if (tid < 128 && row0 + tid < cnt) {
        int n = rowsLds[tid];
        hdot[n] = red[tid * 4] + red[tid * 4 + 1] + red[tid * 4 + 2] + red[tid * 4 + 3];
    }
}

// ---------------------------------------------------------------------------
__global__ __launch_bounds__(256)
void relu_kernel(const float* __restrict__ h, float* __restrict__ out)
{
    int idx = (blockIdx.x * 256 + threadIdx.x) * 4;
    float4 v = *reinterpret_cast<const float4*>(h + idx);
    v.x = fmaxf(v.x, 0.f); v.y = fmaxf(v.y, 0.f);
    v.z = fmaxf(v.z, 0.f); v.w = fmaxf(v.w, 0.f);
    *reinterpret_cast<float4*>(out + idx) = v;
}

// ---------------------------------------------------------------------------
extern "C" void kernel_launch(void* const* d_in, const int* in_sizes, int n_in,
                              void* d_out, int out_size, void* d_ws, size_t ws_size,
                              hipStream_t stream)
{
    (void)in_sizes; (void)n_in; (void)out_size; (void)ws_size;

    const float* x    = (const float*)d_in[0];
    const int*   ei   = (const int*)d_in[1];
    const float* ea   = (const float*)d_in[2];
    const float* We_f = (const float*)d_in[4];
    const float* be_f = (const float*)d_in[5];
    const float* Wa_f = (const float*)d_in[6];
    const float* ba_f = (const float*)d_in[7];
    const float* Wi_f = (const float*)d_in[8];
    const float* Wh_f = (const float*)d_in[9];
    const float* bi_f = (const float*)d_in[10];
    const float* bh_f = (const float*)d_in[11];
    const float* We_b = (const float*)d_in[12];
    const float* be_b = (const float*)d_in[13];
    const float* Wa_b = (const float*)d_in[14];
    const float* ba_b = (const float*)d_in[15];
    const float* Wi_b = (const float*)d_in[16];
    const float* Wh_b = (const float*)d_in[17];
    const float* bi_b = (const float*)d_in[18];
    const float* bh_b = (const float*)d_in[19];
    float* out = (float*)d_out;

    char* p = (char*)d_ws;
    auto carve = [&](size_t bytes) -> char* {
        char* r = p;
        p += (bytes + 255) & ~(size_t)255;
        return r;
    };
    // ---- zeroed region (contiguous, one memset per launch) ----
    int*   counts  = (int*)carve((size_t)16 * 65536 * 4);      // [dir*8+lvl][node]
    int*   cursor  = (int*)carve((size_t)16 * 65536 * 4);
    int*   flag_f  = (int*)carve((size_t)N_NODES * 4);
    int*   flag_b  = (int*)carve((size_t)N_NODES * 4);
    float* h_fwd   = (float*)carve((size_t)N_NODES * D * 4);   // must start at 0
    float* h_cur   = (float*)carve((size_t)N_NODES * D * 4);   // must start at 0
    size_t zbytes  = (size_t)((char*)h_cur - (char*)counts) + (size_t)N_NODES * D * 4;
    // ---- rest (fully written each launch before use) ----
    int*   cnts    = (int*)carve(256);                         // 16 used (scan-written)
    u16*   W_hi    = (u16*)carve((size_t)4 * 49152 * 2);       // WiF,WhF,WiB,WhB
    u16*   W_lo    = (u16*)carve((size_t)4 * 49152 * 2);
    float* u_f     = (float*)carve((size_t)D * 4);
    float* u_b     = (float*)carve((size_t)D * 4);
    float* cst     = (float*)carve(16);
    float* edot_f  = (float*)carve((size_t)E_EDGES * 4);
    float* edot_b  = (float*)carve((size_t)E_EDGES * 4);
    int*   offs    = (int*)carve((size_t)16 * OSTR * 4);
    int2*  csr     = (int2*)carve((size_t)16 * EL * 8);
    int*   rows    = (int*)carve((size_t)16 * 65536 * 4);
    float* msgc    = (float*)carve((size_t)N_NODES * D * 4);   // compacted msg
    float* qdot    = (float*)carve((size_t)N_NODES * 4);
    float* hdot    = (float*)carve((size_t)N_NODES * 4);

    hipMemsetAsync(counts, 0, zbytes, stream);
    prep_kernel<<<1, 256, 0, stream>>>(We_f, Wa_f, be_f, ba_f, We_b, Wa_b, be_b, ba_b,
                                       u_f, u_b, cst);
    convert_w4<<<dim3(192, 4), 256, 0, stream>>>(Wi_f, Wh_f, Wi_b, Wh_b, W_hi, W_lo);
    count_flags<<<E_EDGES / 256, 256, 0, stream>>>(ei, counts, flag_f, flag_b);
    edot_kernel<<<E_EDGES / 4, 256, 0, stream>>>(ea, u_f, u_b, cst, edot_f, edot_b);
    scan_compact<<<16, 1024, 0, stream>>>(counts, offs, rows, cnts);
    fill_csr<<<2 * E_EDGES / 256, 256, 0, stream>>>(ei, edot_f, edot_b, offs, cursor, csr);

    for (int dir = 0; dir < 2; ++dir) {
        const float* hp   = dir == 0 ? x : h_fwd;
        float*       h    = dir == 0 ? h_fwd : h_cur;
        const u16*   Wihi = W_hi + (size_t)(dir * 2) * 49152;
        const u16*   Wilo = W_lo + (size_t)(dir * 2) * 49152;
        const u16*   Whhi = W_hi + (size_t)(dir * 2 + 1) * 49152;
        const u16*   Whlo = W_lo + (size_t)(dir * 2 + 1) * 49152;
        const float* Wi   = dir == 0 ? Wi_f : Wi_b;
        const float* bi   = dir == 0 ? bi_f : bi_b;
        const float* bh   = dir == 0 ? bh_f : bh_b;
        const float* wa   = dir == 0 ? Wa_f : Wa_b;
        const int*   flag = dir == 0 ? flag_f : flag_b;

        root_init<<<N_NODES / 4, 256, 0, stream>>>(hp, flag, Wi, bi, bh, wa,
                                                   h, qdot, hdot);

        for (int t = 0; t < LVLS; ++t) {
            int lv = dir == 0 ? t : (LVLS - 1 - t);
            int dl = dir * LVLS + lv;
            attn_msg<<<2048, 256, 0, stream>>>(
                cnts + dl, rows + (size_t)dl * 65536, offs + (size_t)dl * OSTR,
                csr + (size_t)dl * EL, qdot, hdot, h, msgc);
            gemm_gru<<<512, 512, 0, stream>>>(
                msgc, hp, Whhi, Whlo, Wihi, Wilo,
                cnts + dl, rows + (size_t)dl * 65536,
                bi, bh, wa, h, hdot);
        }
    }
    relu_kernel<<<(N_NODES * D) / 1024, 256, 0, stream>>>(h_cur, out);
}

// Round 11
// 1683.080 us; speedup vs baseline: 5.6595x; 1.0820x over previous
//
#include <hip/hip_runtime.h>
#include <cstdint>
#include <cstddef>

constexpr int N_NODES = 65536;
constexpr int D       = 128;
constexpr int E_EDGES = 524288;
constexpr int LVLS    = 8;
constexpr int EL      = E_EDGES / LVLS;   // 65536
constexpr int OSTR    = 65540;            // offs segment stride (16B-aligned)
constexpr int WIMG_M  = 131072;           // per-matrix image bytes (4 k-steps x 32KB)

typedef unsigned int  u32;
typedef unsigned short u16;
typedef __attribute__((ext_vector_type(8)))  short short8;   // 8 bf16 (4 VGPR)
typedef __attribute__((ext_vector_type(16))) float f32x16;

__device__ __forceinline__ float sigmoidf_(float x) { return 1.0f / (1.0f + expf(-x)); }

__device__ __forceinline__ u32 bf_hi(float f) {           // f32 -> bf16 bits (RNE)
    u32 x = __float_as_uint(f);
    return (x + 0x7fffu + ((x >> 16) & 1u)) >> 16;
}
__device__ __forceinline__ float bf_f(u32 hbits) { return __uint_as_float(hbits << 16); }

// Swizzled byte offset inside a [rows][32 bf16] LDS tile (64B rows).
// XOR of bits 4-5 only: bijective within each 64B row (4x16B slot permute).
__device__ __forceinline__ int swz(int row, int kbyte) {
    return row * 64 + (kbyte ^ ((row & 3) << 4));
}

// wave-level async global->LDS DMA: 64 lanes x 16B. lds dest must be
// wave-uniform; HW writes lds[base + lane*16] (guide section 5).
__device__ __forceinline__ void gload_lds16(const void* g, void* l) {
    __builtin_amdgcn_global_load_lds(
        (const __attribute__((address_space(1))) unsigned int*)g,
        (__attribute__((address_space(3))) unsigned int*)l, 16, 0, 0);
}

__device__ __forceinline__ float wave_sum(float v) {
#pragma unroll
    for (int off = 32; off > 0; off >>= 1) v += __shfl_down(v, off, 64);
    return v;
}

// ---------------------------------------------------------------------------
// u_dir[c] = sum_d We[d][c]*wa2[d];  cst = be.wa2 + ba
__global__ __launch_bounds__(256)
void prep_kernel(const float* __restrict__ We_f, const float* __restrict__ Wa_f,
                 const float* __restrict__ be_f, const float* __restrict__ ba_f,
                 const float* __restrict__ We_b, const float* __restrict__ Wa_b,
                 const float* __restrict__ be_b, const float* __restrict__ ba_b,
                 float* __restrict__ u_f, float* __restrict__ u_b, float* __restrict__ cst)
{
    int t = threadIdx.x;
    if (t < 128) {
        float s = 0.f;
        for (int d = 0; d < 128; ++d) s = fmaf(We_f[d * 128 + t], Wa_f[128 + d], s);
        u_f[t] = s;
    } else {
        int c = t - 128;
        float s = 0.f;
        for (int d = 0; d < 128; ++d) s = fmaf(We_b[d * 128 + c], Wa_b[128 + d], s);
        u_b[c] = s;
    }
    if (t == 0) {
        float s = 0.f;
        for (int d = 0; d < 128; ++d) s = fmaf(be_f[d], Wa_f[128 + d], s);
        cst[0] = s + ba_f[0];
    }
    if (t == 255) {
        float s = 0.f;
        for (int d = 0; d < 128; ++d) s = fmaf(be_b[d], Wa_b[128 + d], s);
        cst[1] = s + ba_b[0];
    }
}

// ---------------------------------------------------------------------------
// Weights -> pre-swizzled per-k-step LDS images (bf16 split).
// Image layout per matrix m (131072 B): [ks 0..3][32KB = hi(384 rows x 64B,
// swizzled) + lo(g=2 slice rows 256..383, 128 x 64B, swizzled)].
// gemm stages each 32KB image verbatim via global_load_lds (linear dest).
__global__ __launch_bounds__(256)
void convert_w4(const float* __restrict__ W0, const float* __restrict__ W1,
                const float* __restrict__ W2, const float* __restrict__ W3,
                unsigned char* __restrict__ img)
{
    const float* Ws[4] = {W0, W1, W2, W3};
    int m = blockIdx.y;
    int i = blockIdx.x * 256 + threadIdx.x;        // < 49152 ; i = rw*128 + k
    int rw = i >> 7, k = i & 127;
    float v = Ws[m][i];
    u32 hb = bf_hi(v);
    u32 lb = bf_hi(v - bf_f(hb));
    int ks = k >> 5, kb = (k & 31) * 2;
    size_t base = (size_t)m * WIMG_M + (size_t)ks * 32768;
    *reinterpret_cast<u16*>(img + base + swz(rw, kb)) = (u16)hb;
    if (rw >= 256)
        *reinterpret_cast<u16*>(img + base + 24576 + swz(rw - 256, kb)) = (u16)lb;
}

// ---------------------------------------------------------------------------
__global__ __launch_bounds__(256)
void edot_kernel(const float* __restrict__ ea, const float* __restrict__ u_f,
                 const float* __restrict__ u_b, const float* __restrict__ cst,
                 float* __restrict__ edot_f, float* __restrict__ edot_b)
{
    int wv = threadIdx.x >> 6, lane = threadIdx.x & 63;
    int e = blockIdx.x * 4 + wv;
    if (e >= E_EDGES) return;
    int d = lane << 1;
    float2 v  = *reinterpret_cast<const float2*>(ea + (size_t)e * 128 + d);
    float2 uf = *reinterpret_cast<const float2*>(u_f + d);
    float2 ub = *reinterpret_cast<const float2*>(u_b + d);
    float af = wave_sum(v.x * uf.x + v.y * uf.y);
    float ab = wave_sum(v.x * ub.x + v.y * ub.y);
    if (lane == 0) {
        edot_f[e] = af + cst[0];
        edot_b[e] = ab + cst[1];
    }
}

// ---------------------------------------------------------------------------
// per-(dir,level) target counts + direction flags. dl = dir*8+lvl.
__global__ __launch_bounds__(256)
void count_flags(const int* __restrict__ ei, int* __restrict__ counts,
                 int* __restrict__ flag_f, int* __restrict__ flag_b)
{
    int e = blockIdx.x * 256 + threadIdx.x;
    int lv = e >> 16;
    int s = ei[e], t = ei[E_EDGES + e];
    atomicAdd(&counts[(size_t)lv * 65536 + t], 1);           // fwd: target = dst
    atomicAdd(&counts[(size_t)(8 + lv) * 65536 + s], 1);     // bwd: target = src
    flag_f[t] = 1;
    flag_b[s] = 1;
}

// ---------------------------------------------------------------------------
// Per dl-segment: exclusive scan of counts -> offs[OSTR], AND compaction of
// nonzero-count nodes -> rows (sorted, deterministic) + cnts[dl]. No atomics.
__global__ __launch_bounds__(1024)
void scan_compact(const int* __restrict__ counts, int* __restrict__ offs,
                  int* __restrict__ rows, int* __restrict__ cnts)
{
    __shared__ int sbuf[1024];
    __shared__ int nbuf[1024];
    int dl = blockIdx.x;
    const int4* c4 = reinterpret_cast<const int4*>(counts + (size_t)dl * 65536);
    int* o = offs + (size_t)dl * OSTR;
    int* rw = rows + (size_t)dl * 65536;
    int t = threadIdx.x;
    int cv[64];
#pragma unroll 4
    for (int k4 = 0; k4 < 16; ++k4) {
        int4 v = c4[t * 16 + k4];
        cv[k4 * 4 + 0] = v.x; cv[k4 * 4 + 1] = v.y;
        cv[k4 * 4 + 2] = v.z; cv[k4 * 4 + 3] = v.w;
    }
    int s = 0, nz = 0;
#pragma unroll
    for (int k = 0; k < 64; ++k) { s += cv[k]; nz += (cv[k] > 0); }
    sbuf[t] = s;
    nbuf[t] = nz;
    __syncthreads();
    int val = s, nval = nz;
    for (int off = 1; off < 1024; off <<= 1) {
        int add  = (t >= off) ? sbuf[t - off] : 0;
        int nadd = (t >= off) ? nbuf[t - off] : 0;
        __syncthreads();
        val += add;
        nval += nadd;
        sbuf[t] = val;
        nbuf[t] = nval;
        __syncthreads();
    }
    int run  = val - s;    // exclusive prefix of edge counts
    int nrun = nval - nz;  // exclusive prefix of nonzero predicate
    int base = t * 64;
    int4* o4 = reinterpret_cast<int4*>(o + base);
#pragma unroll 4
    for (int k4 = 0; k4 < 16; ++k4) {
        int4 ov;
        ov.x = run; run += cv[k4 * 4 + 0];
        ov.y = run; run += cv[k4 * 4 + 1];
        ov.z = run; run += cv[k4 * 4 + 2];
        ov.w = run; run += cv[k4 * 4 + 3];
        o4[k4] = ov;
#pragma unroll
        for (int q = 0; q < 4; ++q)
            if (cv[k4 * 4 + q] > 0) rw[nrun++] = base + k4 * 4 + q;
    }
    if (t == 1023) { o[65536] = val; cnts[dl] = nval; }
}

// ---------------------------------------------------------------------------
// fill CSR entries: per edge, slot = dl*EL + offs[i] + cursor++ ; store {j, edot}
__global__ __launch_bounds__(256)
void fill_csr(const int* __restrict__ ei, const float* __restrict__ edot_f,
              const float* __restrict__ edot_b, const int* __restrict__ offs,
              int* __restrict__ cursor, int2* __restrict__ csr)
{
    int idx = blockIdx.x * 256 + threadIdx.x;       // < 2E
    int dir = idx >= E_EDGES;
    int ge = dir ? idx - E_EDGES : idx;
    int lv = ge >> 16;
    int dl = dir * 8 + lv;
    int i = dir ? ei[ge] : ei[E_EDGES + ge];
    int j = dir ? ei[E_EDGES + ge] : ei[ge];
    int pos = offs[(size_t)dl * OSTR + i] + atomicAdd(&cursor[(size_t)dl * 65536 + i], 1);
    int2 v;
    v.x = j;
    v.y = __float_as_int(dir ? edot_b[ge] : edot_f[ge]);
    csr[(size_t)dl * EL + pos] = v;
}

// ---------------------------------------------------------------------------
// Per direction init: qdot[n] = hp[n].wa1 for ALL n; for roots (flag==0):
// h = (1-z)*tanh(...) exact f32, hdot = h.wa2; non-roots: hdot = 0
// (h zeroed by launch memset). Wave per node.
__global__ __launch_bounds__(256)
void root_init(const float* __restrict__ hp, const int* __restrict__ flag,
               const float* __restrict__ Wi, const float* __restrict__ bi,
               const float* __restrict__ bh, const float* __restrict__ wa,
               float* __restrict__ h, float* __restrict__ qdot,
               float* __restrict__ hdot)
{
    int wv = threadIdx.x >> 6, lane = threadIdx.x & 63;
    int n = blockIdx.x * 4 + wv;
    int d = lane << 1;
    const float* hprow = hp + (size_t)n * 128;
    float2 hpv = *reinterpret_cast<const float2*>(hprow + d);
    float qd = wave_sum(hpv.x * wa[d] + hpv.y * wa[d + 1]);
    if (lane == 0) qdot[n] = qd;
    bool root = (flag[n] == 0);
    float hv[2] = {0.f, 0.f};
    if (root) {   // rare; exact f32 path
#pragma unroll
        for (int q = 0; q < 2; ++q) {
            int dd = d + q;
            float g0 = bi[dd], g1 = bi[dd + 128], g2 = bi[dd + 256];
            for (int k = 0; k < 128; ++k) {
                float a = hprow[k];
                g0 = fmaf(a, Wi[(size_t)dd * 128 + k], g0);
                g1 = fmaf(a, Wi[(size_t)(dd + 128) * 128 + k], g1);
                g2 = fmaf(a, Wi[(size_t)(dd + 256) * 128 + k], g2);
            }
            float rr = sigmoidf_(g0 + bh[dd]);
            float zz = sigmoidf_(g1 + bh[dd + 128]);
            float nn = tanhf(g2 + rr * bh[dd + 256]);
            hv[q] = (1.f - zz) * nn;            // hidden = 0 for roots
        }
        *reinterpret_cast<float2*>(h + (size_t)n * 128 + d) = make_float2(hv[0], hv[1]);
    }
    float hd = wave_sum(hv[0] * wa[128 + d] + hv[1] * wa[128 + d + 1]);
    if (lane == 0) hdot[n] = root ? hd : 0.f;
}

// ---------------------------------------------------------------------------
// Half-wave (32 lanes) per target: single-pass softmax-weighted aggregation.
__global__ __launch_bounds__(256)
void attn_msg(const int* __restrict__ pcnt, const int* __restrict__ rows,
              const int* __restrict__ offs, const int2* __restrict__ csr,
              const float* __restrict__ qdot, const float* __restrict__ hdot,
              const float* __restrict__ h, float* __restrict__ msgc)
{
    int cnt = *pcnt;
    int l31 = threadIdx.x & 31;
    int hid = (blockIdx.x * 256 + threadIdx.x) >> 5;
    int nh = (gridDim.x * 256) >> 5;
    int d4 = l31 << 2;
    for (int r = hid; r < cnt; r += nh) {
        int i = rows[r];
        int o0 = offs[i], o1 = offs[i + 1];
        float qi = qdot[i];
        float den = 0.f;
        float4 acc = make_float4(0.f, 0.f, 0.f, 0.f);
        for (int e = o0; e < o1; ++e) {
            int2 je = csr[e];
            float ex = expf(qi + hdot[je.x] + __int_as_float(je.y));
            float4 hv = *reinterpret_cast<const float4*>(h + (size_t)je.x * 128 + d4);
            den += ex;
            acc.x = fmaf(ex, hv.x, acc.x);
            acc.y = fmaf(ex, hv.y, acc.y);
            acc.z = fmaf(ex, hv.z, acc.z);
            acc.w = fmaf(ex, hv.w, acc.w);
        }
        float inv = 1.f / den;
        *reinterpret_cast<float4*>(msgc + (size_t)r * 128 + d4) =
            make_float4(acc.x * inv, acc.y * inv, acc.z * inv, acc.w * inv);
    }
}

// ---------------------------------------------------------------------------
// Dual-phase split-bf16 MFMA GEMM + GRU epilogue (per level).
// Phase A: acc  = msgc[dense rows] @ Wh^T   (gh; gh_n stashed, slice zeroed)
// Phase B: acc += hp[gathered rows] @ Wi^T
// Precision: r/z gates = (Ah+Al)*Bh (2 MFMA); n gate = Ah*Bh+Ah*Bl+Al*Bh (3).
// B staged via global_load_lds from pre-swizzled weight images (32KB/k-step).
__global__ __launch_bounds__(512, 1)
void gemm_gru(const float* __restrict__ msgc, const float* __restrict__ hp,
              const unsigned char* __restrict__ WhImg,
              const unsigned char* __restrict__ WiImg,
              const int* __restrict__ pcnt, const int* __restrict__ rows,
              const float* __restrict__ bi, const float* __restrict__ bh,
              const float* __restrict__ wa,
              float* __restrict__ h, float* __restrict__ hdot)
{
    __shared__ __align__(16) unsigned char smem[16384 + 32768 + 2048 + 512];
    unsigned char* As = smem;               // [2 halves][128][32 bf16] swizzled
    unsigned char* Bs = smem + 16384;       // hi 384x64B + lo(g2) 128x64B swizzled
    float* red   = (float*)(smem + 16384 + 32768);      // [128][4]
    int* rowsLds = (int*)(smem + 16384 + 32768 + 2048); // [128]

    const int tid = threadIdx.x;
    const int cnt = *pcnt;
    const int row0 = blockIdx.x * 128;
    if (row0 >= cnt) return;

    if (tid < 128) {
        int gr = row0 + tid;
        rowsLds[tid] = (gr < cnt) ? rows[gr] : 0;   // clamp stale entries
    }
    __syncthreads();

    f32x16 acc[2][3];
#pragma unroll
    for (int mt = 0; mt < 2; ++mt)
#pragma unroll
        for (int g = 0; g < 3; ++g) acc[mt][g] = (f32x16)0.0f;
    f32x16 ghn[2];

    const int lane = tid & 63, wv = tid >> 6;
    const int q = wv & 3, mh = wv >> 2;
    const int l31 = lane & 31, l5 = lane >> 5;

#pragma unroll
    for (int ph = 0; ph < 2; ++ph) {
        const float* Asrc = ph ? hp : msgc;
        const unsigned char* Bimg = ph ? WiImg : WhImg;
        for (int ks = 0; ks < 4; ++ks) {
            int k0 = ks * 32;
            // ---- stage B: 32KB DMA (4 x 1KB per wave) from pre-swizzled image
            {
                const unsigned char* src = Bimg + (size_t)ks * 32768 + wv * 4096 + lane * 16;
                unsigned char* dst = Bs + wv * 4096;
                gload_lds16(src,        dst);
                gload_lds16(src + 1024, dst + 1024);
                gload_lds16(src + 2048, dst + 2048);
                gload_lds16(src + 3072, dst + 3072);
            }
            // ---- stage A (f32 -> bf16 hi/lo): 128 rows x 32 k
#pragma unroll
            for (int p = 0; p < 2; ++p) {
                int idx = tid + p * 512;
                int rw = idx >> 3, kf = (idx & 7) << 2;
                int arow = ph ? rowsLds[rw] : (row0 + rw);
                float4 v = *reinterpret_cast<const float4*>(Asrc + (size_t)arow * 128 + k0 + kf);
                u32 h0 = bf_hi(v.x), h1 = bf_hi(v.y), h2 = bf_hi(v.z), h3 = bf_hi(v.w);
                u32 l0 = bf_hi(v.x - bf_f(h0)), l1 = bf_hi(v.y - bf_f(h1));
                u32 l2 = bf_hi(v.z - bf_f(h2)), l3 = bf_hi(v.w - bf_f(h3));
                int off = swz(rw, kf * 2);
                *reinterpret_cast<uint2*>(As + off)        = make_uint2(h0 | (h1 << 16), h2 | (h3 << 16));
                *reinterpret_cast<uint2*>(As + 8192 + off) = make_uint2(l0 | (l1 << 16), l2 | (l3 << 16));
            }
            __syncthreads();   // drains vmcnt (DMA) + lgkmcnt (ds_writes)
            // ---- MFMA
#pragma unroll
            for (int kh = 0; kh < 2; ++kh) {
                short8 a[2][2];
#pragma unroll
                for (int mt = 0; mt < 2; ++mt)
#pragma unroll
                    for (int hf = 0; hf < 2; ++hf)
                        a[mt][hf] = *reinterpret_cast<const short8*>(
                            As + hf * 8192 + swz(mh * 64 + mt * 32 + l31, kh * 32 + l5 * 16));
                short8 bh0 = *reinterpret_cast<const short8*>(
                    Bs + swz(q * 32 + l31, kh * 32 + l5 * 16));
                short8 bh1 = *reinterpret_cast<const short8*>(
                    Bs + swz(q * 32 + 128 + l31, kh * 32 + l5 * 16));
                short8 bh2 = *reinterpret_cast<const short8*>(
                    Bs + swz(q * 32 + 256 + l31, kh * 32 + l5 * 16));
                short8 bl2 = *reinterpret_cast<const short8*>(
                    Bs + 24576 + swz(q * 32 + l31, kh * 32 + l5 * 16));
#pragma unroll
                for (int mt = 0; mt < 2; ++mt) {
                    acc[mt][0] = __builtin_amdgcn_mfma_f32_32x32x16_bf16(a[mt][0], bh0, acc[mt][0], 0, 0, 0);
                    acc[mt][0] = __builtin_amdgcn_mfma_f32_32x32x16_bf16(a[mt][1], bh0, acc[mt][0], 0, 0, 0);
                    acc[mt][1] = __builtin_amdgcn_mfma_f32_32x32x16_bf16(a[mt][0], bh1, acc[mt][1], 0, 0, 0);
                    acc[mt][1] = __builtin_amdgcn_mfma_f32_32x32x16_bf16(a[mt][1], bh1, acc[mt][1], 0, 0, 0);
                    acc[mt][2] = __builtin_amdgcn_mfma_f32_32x32x16_bf16(a[mt][0], bh2, acc[mt][2], 0, 0, 0);
                    acc[mt][2] = __builtin_amdgcn_mfma_f32_32x32x16_bf16(a[mt][0], bl2, acc[mt][2], 0, 0, 0);
                    acc[mt][2] = __builtin_amdgcn_mfma_f32_32x32x16_bf16(a[mt][1], bh2, acc[mt][2], 0, 0, 0);
                }
            }
            __syncthreads();
        }
        if (ph == 0) {                       // stash gh_n, zero its slice
            ghn[0] = acc[0][2];
            ghn[1] = acc[1][2];
            acc[0][2] = (f32x16)0.0f;
            acc[1][2] = (f32x16)0.0f;
        }
    }

    // ---- epilogue
    const int d = q * 32 + l31;
    const float wa2d = wa[128 + d];
    const float bi0 = bi[d], bi1 = bi[d + 128], bi2 = bi[d + 256];
    const float bh0 = bh[d], bh1 = bh[d + 128], bh2 = bh[d + 256];

#pragma unroll
    for (int mt = 0; mt < 2; ++mt)
#pragma unroll
        for (int rg = 0; rg < 16; ++rg) {
            int rl = mh * 64 + mt * 32 + (rg & 3) + ((rg >> 2) << 3) + (l5 << 2);
            int gr = row0 + rl;
            bool ok = gr < cnt;
            int n = rowsLds[rl];
            float mval = msgc[(size_t)gr * 128 + d];   // dense; gr < 65536 always
            float rr = sigmoidf_(acc[mt][0][rg] + bi0 + bh0);
            float zz = sigmoidf_(acc[mt][1][rg] + bi1 + bh1);
            float nn = tanhf(acc[mt][2][rg] + bi2 + rr * (ghn[mt][rg] + bh2));
            float hv = (1.f - zz) * nn + zz * mval;    // hidden = msg
            if (ok) h[(size_t)n * 128 + d] = hv;
            float pd = hv * wa2d;
#pragma unroll
            for (int o = 1; o < 32; o <<= 1) pd += __shfl_xor(pd, o, 64);
            if (l31 == 0) red[rl * 4 + q] = pd;
        }
    __syncthreads();
    if (tid < 128 && row0 + tid < cnt) {
        int n = rowsLds[tid];
        hdot[n] = red[tid * 4] + red[tid * 4 + 1] + red[tid * 4 + 2] + red[tid * 4 + 3];
    }
}

// ---------------------------------------------------------------------------
__global__ __launch_bounds__(256)
void relu_kernel(const float* __restrict__ h, float* __restrict__ out)
{
    int idx = (blockIdx.x * 256 + threadIdx.x) * 4;
    float4 v = *reinterpret_cast<const float4*>(h + idx);
    v.x = fmaxf(v.x, 0.f); v.y = fmaxf(v.y, 0.f);
    v.z = fmaxf(v.z, 0.f); v.w = fmaxf(v.w, 0.f);
    *reinterpret_cast<float4*>(out + idx) = v;
}

// ---------------------------------------------------------------------------
extern "C" void kernel_launch(void* const* d_in, const int* in_sizes, int n_in,
                              void* d_out, int out_size, void* d_ws, size_t ws_size,
                              hipStream_t stream)
{
    (void)in_sizes; (void)n_in; (void)out_size; (void)ws_size;

    const float* x    = (const float*)d_in[0];
    const int*   ei   = (const int*)d_in[1];
    const float* ea   = (const float*)d_in[2];
    const float* We_f = (const float*)d_in[4];
    const float* be_f = (const float*)d_in[5];
    const float* Wa_f = (const float*)d_in[6];
    const float* ba_f = (const float*)d_in[7];
    const float* Wi_f = (const float*)d_in[8];
    const float* Wh_f = (const float*)d_in[9];
    const float* bi_f = (const float*)d_in[10];
    const float* bh_f = (const float*)d_in[11];
    const float* We_b = (const float*)d_in[12];
    const float* be_b = (const float*)d_in[13];
    const float* Wa_b = (const float*)d_in[14];
    const float* ba_b = (const float*)d_in[15];
    const float* Wi_b = (const float*)d_in[16];
    const float* Wh_b = (const float*)d_in[17];
    const float* bi_b = (const float*)d_in[18];
    const float* bh_b = (const float*)d_in[19];
    float* out = (float*)d_out;

    char* p = (char*)d_ws;
    auto carve = [&](size_t bytes) -> char* {
        char* r = p;
        p += (bytes + 255) & ~(size_t)255;
        return r;
    };
    // ---- zeroed region (contiguous, one memset per launch) ----
    int*   counts  = (int*)carve((size_t)16 * 65536 * 4);      // [dir*8+lvl][node]
    int*   cursor  = (int*)carve((size_t)16 * 65536 * 4);
    int*   flag_f  = (int*)carve((size_t)N_NODES * 4);
    int*   flag_b  = (int*)carve((size_t)N_NODES * 4);
    float* h_fwd   = (float*)carve((size_t)N_NODES * D * 4);   // must start at 0
    float* h_cur   = (float*)carve((size_t)N_NODES * D * 4);   // must start at 0
    size_t zbytes  = (size_t)((char*)h_cur - (char*)counts) + (size_t)N_NODES * D * 4;
    // ---- rest (fully written each launch before use) ----
    int*   cnts    = (int*)carve(256);                         // 16 used (scan-written)
    unsigned char* Wimg = (unsigned char*)carve((size_t)4 * WIMG_M); // WiF,WhF,WiB,WhB images
    float* u_f     = (float*)carve((size_t)D * 4);
    float* u_b     = (float*)carve((size_t)D * 4);
    float* cst     = (float*)carve(16);
    float* edot_f  = (float*)carve((size_t)E_EDGES * 4);
    float* edot_b  = (float*)carve((size_t)E_EDGES * 4);
    int*   offs    = (int*)carve((size_t)16 * OSTR * 4);
    int2*  csr     = (int2*)carve((size_t)16 * EL * 8);
    int*   rows    = (int*)carve((size_t)16 * 65536 * 4);
    float* msgc    = (float*)carve((size_t)N_NODES * D * 4);   // compacted msg
    float* qdot    = (float*)carve((size_t)N_NODES * 4);
    float* hdot    = (float*)carve((size_t)N_NODES * 4);

    hipMemsetAsync(counts, 0, zbytes, stream);
    prep_kernel<<<1, 256, 0, stream>>>(We_f, Wa_f, be_f, ba_f, We_b, Wa_b, be_b, ba_b,
                                       u_f, u_b, cst);
    convert_w4<<<dim3(192, 4), 256, 0, stream>>>(Wi_f, Wh_f, Wi_b, Wh_b, Wimg);
    count_flags<<<E_EDGES / 256, 256, 0, stream>>>(ei, counts, flag_f, flag_b);
    edot_kernel<<<E_EDGES / 4, 256, 0, stream>>>(ea, u_f, u_b, cst, edot_f, edot_b);
    scan_compact<<<16, 1024, 0, stream>>>(counts, offs, rows, cnts);
    fill_csr<<<2 * E_EDGES / 256, 256, 0, stream>>>(ei, edot_f, edot_b, offs, cursor, csr);

    for (int dir = 0; dir < 2; ++dir) {
        const float* hp   = dir == 0 ? x : h_fwd;
        float*       h    = dir == 0 ? h_fwd : h_cur;
        const unsigned char* WiImg = Wimg + (size_t)(dir * 2) * WIMG_M;
        const unsigned char* WhImg = Wimg + (size_t)(dir * 2 + 1) * WIMG_M;
        const float* Wi   = dir == 0 ? Wi_f : Wi_b;
        const float* bi   = dir == 0 ? bi_f : bi_b;
        const float* bh   = dir == 0 ? bh_f : bh_b;
        const float* wa   = dir == 0 ? Wa_f : Wa_b;
        const int*   flag = dir == 0 ? flag_f : flag_b;

        root_init<<<N_NODES / 4, 256, 0, stream>>>(hp, flag, Wi, bi, bh, wa,
                                                   h, qdot, hdot);

        for (int t = 0; t < LVLS; ++t) {
            int lv = dir == 0 ? t : (LVLS - 1 - t);
            int dl = dir * LVLS + lv;
            attn_msg<<<2048, 256, 0, stream>>>(
                cnts + dl, rows + (size_t)dl * 65536, offs + (size_t)dl * OSTR,
                csr + (size_t)dl * EL, qdot, hdot, h, msgc);
            gemm_gru<<<512, 512, 0, stream>>>(
                msgc, hp, WhImg, WiImg,
                cnts + dl, rows + (size_t)dl * 65536,
                bi, bh, wa, h, hdot);
        }
    }
    relu_kernel<<<(N_NODES * D) / 1024, 256, 0, stream>>>(h_cur, out);
}